// Round 1
// baseline (762.118 us; speedup 1.0000x reference)
//
#include <hip/hip_runtime.h>
#include <math.h>

#define BB   4
#define SS   2048
#define EE   512
#define HH   8
#define DH   64
#define WW   128
#define MM   (BB*SS)      // 8192

// ---------------------------------------------------------------------------
// QKV GEMM: qkv[m,n] = emb[m,:] . in_proj_w[n,:] + b[n]  (B^T layout GEMM)
// scatter epilogue into q/k/v [B,H,S,DH]
// ---------------------------------------------------------------------------
__global__ __launch_bounds__(256) void qkv_gemm(
    const float* __restrict__ A, const float* __restrict__ Wt,
    const float* __restrict__ bias,
    float* __restrict__ qd, float* __restrict__ kd, float* __restrict__ vd)
{
    __shared__ float As[16][64];
    __shared__ float Bs[16][64];
    const int tid = threadIdx.x;
    const int m0 = blockIdx.x * 64;
    const int n0 = blockIdx.y * 64;
    const int tx = tid & 15, ty = tid >> 4;
    const int r = tid >> 2, c = tid & 3;

    float acc[4][4] = {};
    for (int k0 = 0; k0 < 512; k0 += 16) {
        float4 av = *(const float4*)(A  + (size_t)(m0 + r)*512 + k0 + c*4);
        float4 bv = *(const float4*)(Wt + (size_t)(n0 + r)*512 + k0 + c*4);
        As[c*4+0][r] = av.x; As[c*4+1][r] = av.y; As[c*4+2][r] = av.z; As[c*4+3][r] = av.w;
        Bs[c*4+0][r] = bv.x; Bs[c*4+1][r] = bv.y; Bs[c*4+2][r] = bv.z; Bs[c*4+3][r] = bv.w;
        __syncthreads();
        #pragma unroll
        for (int kk = 0; kk < 16; ++kk) {
            float4 a4 = *(const float4*)(&As[kk][ty*4]);
            float4 b4 = *(const float4*)(&Bs[kk][tx*4]);
            float aa[4] = {a4.x, a4.y, a4.z, a4.w};
            float bb[4] = {b4.x, b4.y, b4.z, b4.w};
            #pragma unroll
            for (int i = 0; i < 4; ++i)
                #pragma unroll
                for (int j = 0; j < 4; ++j)
                    acc[i][j] += aa[i] * bb[j];
        }
        __syncthreads();
    }

    // epilogue: n0 block is 64-aligned -> same head, same q/k/v selector
    const int which = n0 >> 9;             // 0=q 1=k 2=v
    const int h = (n0 >> 6) & 7;
    const int d0 = tx * 4;
    float* dst = (which == 0) ? qd : (which == 1) ? kd : vd;
    #pragma unroll
    for (int i = 0; i < 4; ++i) {
        int m = m0 + ty*4 + i;
        int b = m >> 11, s = m & 2047;
        float4 o;
        o.x = acc[i][0] + bias[n0 + d0 + 0];
        o.y = acc[i][1] + bias[n0 + d0 + 1];
        o.z = acc[i][2] + bias[n0 + d0 + 2];
        o.w = acc[i][3] + bias[n0 + d0 + 3];
        *(float4*)(dst + (((size_t)(b*HH + h))*SS + s)*DH + d0) = o;
    }
}

// ---------------------------------------------------------------------------
// Banded attention: block = (b, 32-row Q tile), loops 8 heads.
// Key window [i0-128, i0+31+128] (<=288) contains every row's full band ->
// exact softmax. Head-averaged probs accumulate in registers -> weights out.
// ---------------------------------------------------------------------------
#define QB 32
#define SW 289   // padded score stride (odd -> LDS-bank friendly)

__global__ __launch_bounds__(512) void attn_kernel(
    const float* __restrict__ qd, const float* __restrict__ kd,
    const float* __restrict__ vd, float* __restrict__ ctx,
    float* __restrict__ wout)
{
    __shared__ float qs[QB][DH];
    __shared__ float sc[QB * SW];

    const int tid = threadIdx.x;
    const int b  = blockIdx.y;
    const int i0 = blockIdx.x * QB;
    const int jlo = (i0 - WW > 0) ? i0 - WW : 0;
    const int jhi = (i0 + QB - 1 + WW < SS - 1) ? i0 + QB - 1 + WW : SS - 1;
    const int nj = jhi - jlo + 1;          // <= 288

    const int qi   = tid >> 4;             // 0..31 (softmax/PV row)
    const int part = tid & 15;             // 0..15
    const int qh   = tid >> 8;             // 0/1 (score phase row-half)
    const int jj0  = tid & 255;

    float waccr[18];
    #pragma unroll
    for (int t = 0; t < 18; ++t) waccr[t] = 0.f;

    for (int h = 0; h < HH; ++h) {
        const float* qbase = qd + ((size_t)(b*HH + h))*SS*DH;
        const float* kbase = kd + ((size_t)(b*HH + h))*SS*DH;
        const float* vbase = vd + ((size_t)(b*HH + h))*SS*DH;

        // stage Q tile
        for (int idx = tid; idx < QB*DH; idx += 512)
            qs[idx >> 6][idx & 63] = qbase[(size_t)(i0 + (idx >> 6))*DH + (idx & 63)];
        __syncthreads();   // also orders prev head's PV reads before sc writes

        // ---- scores: thread owns one key column (16 rows) ----
        for (int jj = jj0; jj < nj; jj += 256) {
            const int j = jlo + jj;
            const float* krow = kbase + (size_t)j * DH;
            float s[16] = {};
            #pragma unroll
            for (int d4 = 0; d4 < DH; d4 += 4) {
                float4 kv = *(const float4*)(krow + d4);
                #pragma unroll
                for (int q2 = 0; q2 < 16; ++q2) {
                    float4 qv = *(const float4*)(&qs[qh*16 + q2][d4]);
                    s[q2] += qv.x*kv.x + qv.y*kv.y + qv.z*kv.z + qv.w*kv.w;
                }
            }
            #pragma unroll
            for (int q2 = 0; q2 < 16; ++q2) {
                int i = i0 + qh*16 + q2;
                int dd = i - j; if (dd < 0) dd = -dd;
                sc[(qh*16 + q2)*SW + jj] = (dd <= WW) ? s[q2] * 0.125f : -1e30f;
            }
        }
        __syncthreads();

        // ---- exact softmax: 16 threads per row ----
        float mrow = -1e30f;
        #pragma unroll
        for (int t = 0; t < 18; ++t) {
            int jj = part + (t << 4);
            if (jj < nj) mrow = fmaxf(mrow, sc[qi*SW + jj]);
        }
        #pragma unroll
        for (int o = 1; o < 16; o <<= 1) mrow = fmaxf(mrow, __shfl_xor(mrow, o));

        float ssum = 0.f;
        float ev[18];
        #pragma unroll
        for (int t = 0; t < 18; ++t) {
            int jj = part + (t << 4);
            if (jj < nj) { float e = __expf(sc[qi*SW + jj] - mrow); ev[t] = e; ssum += e; }
            else ev[t] = 0.f;
        }
        #pragma unroll
        for (int o = 1; o < 16; o <<= 1) ssum += __shfl_xor(ssum, o);
        const float inv = 1.0f / ssum;

        #pragma unroll
        for (int t = 0; t < 18; ++t) {
            int jj = part + (t << 4);
            if (jj < nj) {
                float p = ev[t] * inv;
                sc[qi*SW + jj] = p;
                waccr[t] += 0.125f * p;     // head average
            }
        }
        __syncthreads();

        // ---- PV: thread owns (row qi, 4 dims) ----
        const int d0 = part * 4;
        float cacc[4] = {};
        for (int jj = 0; jj < nj; ++jj) {
            float p = sc[qi*SW + jj];
            float4 vv = *(const float4*)(vbase + (size_t)(jlo + jj)*DH + d0);
            cacc[0] += p*vv.x; cacc[1] += p*vv.y; cacc[2] += p*vv.z; cacc[3] += p*vv.w;
        }
        float4 o = make_float4(cacc[0], cacc[1], cacc[2], cacc[3]);
        *(float4*)(ctx + ((size_t)(b*SS + i0 + qi))*EE + h*DH + d0) = o;
        // next iteration's first __syncthreads() orders sc reuse
    }

    // ---- head-averaged weights (band region only; rest is memset 0) ----
    #pragma unroll
    for (int t = 0; t < 18; ++t) {
        int jj = part + (t << 4);
        if (jj < nj)
            wout[((size_t)(b*SS + i0 + qi))*SS + jlo + jj] = waccr[t];
    }
}

// ---------------------------------------------------------------------------
// Out-proj GEMM with fused per-tile column max (pooled partial)
// part[mtile, n] = max over tile's 64 rows of (ctx @ out_w^T + out_b)[.., n]
// ---------------------------------------------------------------------------
__global__ __launch_bounds__(256) void out_gemm(
    const float* __restrict__ A, const float* __restrict__ Wt,
    const float* __restrict__ bias, float* __restrict__ part)
{
    __shared__ float As[16][64];
    __shared__ float Bs[16][64];
    __shared__ float red[16][64];
    const int tid = threadIdx.x;
    const int m0 = blockIdx.x * 64;
    const int n0 = blockIdx.y * 64;
    const int tx = tid & 15, ty = tid >> 4;
    const int r = tid >> 2, c = tid & 3;

    float acc[4][4] = {};
    for (int k0 = 0; k0 < 512; k0 += 16) {
        float4 av = *(const float4*)(A  + (size_t)(m0 + r)*512 + k0 + c*4);
        float4 bv = *(const float4*)(Wt + (size_t)(n0 + r)*512 + k0 + c*4);
        As[c*4+0][r] = av.x; As[c*4+1][r] = av.y; As[c*4+2][r] = av.z; As[c*4+3][r] = av.w;
        Bs[c*4+0][r] = bv.x; Bs[c*4+1][r] = bv.y; Bs[c*4+2][r] = bv.z; Bs[c*4+3][r] = bv.w;
        __syncthreads();
        #pragma unroll
        for (int kk = 0; kk < 16; ++kk) {
            float4 a4 = *(const float4*)(&As[kk][ty*4]);
            float4 b4 = *(const float4*)(&Bs[kk][tx*4]);
            float aa[4] = {a4.x, a4.y, a4.z, a4.w};
            float bb[4] = {b4.x, b4.y, b4.z, b4.w};
            #pragma unroll
            for (int i = 0; i < 4; ++i)
                #pragma unroll
                for (int j = 0; j < 4; ++j)
                    acc[i][j] += aa[i] * bb[j];
        }
        __syncthreads();
    }

    float lm[4] = {-1e30f, -1e30f, -1e30f, -1e30f};
    #pragma unroll
    for (int i = 0; i < 4; ++i)
        #pragma unroll
        for (int j = 0; j < 4; ++j)
            lm[j] = fmaxf(lm[j], acc[i][j]);
    #pragma unroll
    for (int j = 0; j < 4; ++j) red[ty][tx*4 + j] = lm[j];
    __syncthreads();
    if (tid < 64) {
        float m = red[0][tid];
        #pragma unroll
        for (int t = 1; t < 16; ++t) m = fmaxf(m, red[t][tid]);
        part[(size_t)blockIdx.x * EE + n0 + tid] = m + bias[n0 + tid];
    }
}

// pooled[b,e] = max over the 32 row-tiles of batch b
__global__ void pool_final(const float* __restrict__ part, float* __restrict__ pooled)
{
    int e = blockIdx.x * 256 + threadIdx.x;   // grid.x = 2
    int b = blockIdx.y;
    float m = -1e30f;
    #pragma unroll
    for (int t = 0; t < 32; ++t)
        m = fmaxf(m, part[((size_t)(b*32 + t))*EE + e]);
    pooled[b*EE + e] = m;
}

// ---------------------------------------------------------------------------
extern "C" void kernel_launch(void* const* d_in, const int* in_sizes, int n_in,
                              void* d_out, int out_size, void* d_ws, size_t ws_size,
                              hipStream_t stream)
{
    const float* emb = (const float*)d_in[0];
    const float* ipw = (const float*)d_in[1];
    const float* ipb = (const float*)d_in[2];
    const float* ow  = (const float*)d_in[3];
    const float* ob  = (const float*)d_in[4];

    float* pooled = (float*)d_out;                       // [4,512]
    float* wout   = pooled + (size_t)BB*EE;              // [4,2048,2048]

    const size_t headsz = (size_t)BB*HH*SS*DH;           // 4.19M floats
    float* q    = (float*)d_ws;
    float* k    = q + headsz;
    float* v    = k + headsz;
    float* ctx  = v + headsz;                            // [8192,512]
    float* part = ctx + (size_t)MM*EE;                   // [128,512]

    hipMemsetAsync(wout, 0, (size_t)BB*SS*SS*sizeof(float), stream);
    qkv_gemm<<<dim3(128, 24), 256, 0, stream>>>(emb, ipw, ipb, q, k, v);
    attn_kernel<<<dim3(SS/QB, BB), 512, 0, stream>>>(q, k, v, ctx, wout);
    out_gemm<<<dim3(128, 8), 256, 0, stream>>>(ctx, ow, ob, part);
    pool_final<<<dim3(2, BB), 256, 0, stream>>>(part, pooled);
}

// Round 2
// 753.544 us; speedup vs baseline: 1.0114x; 1.0114x over previous
//
#include <hip/hip_runtime.h>
#include <hip/hip_bf16.h>
#include <math.h>

#define BB   4
#define SS   2048
#define EE   512
#define HH   8
#define DH   64
#define WW   128
#define MM   (BB*SS)      // 8192
#define NTILE (SS/32)     // 64 q-tiles per batch
#define SW   289          // padded score stride (odd -> LDS-bank friendly)
#define PBW  288          // probs buffer stride

// ---------------------------------------------------------------------------
// QKV GEMM: qkv[m,n] = emb[m,:] . in_proj_w[n,:] + b[n]  (B^T layout GEMM)
// scatter epilogue into q/k/v [B,H,S,DH]
// ---------------------------------------------------------------------------
__global__ __launch_bounds__(256) void qkv_gemm(
    const float* __restrict__ A, const float* __restrict__ Wt,
    const float* __restrict__ bias,
    float* __restrict__ qd, float* __restrict__ kd, float* __restrict__ vd)
{
    __shared__ float As[16][64];
    __shared__ float Bs[16][64];
    const int tid = threadIdx.x;
    const int m0 = blockIdx.x * 64;
    const int n0 = blockIdx.y * 64;
    const int tx = tid & 15, ty = tid >> 4;
    const int r = tid >> 2, c = tid & 3;

    float acc[4][4] = {};
    for (int k0 = 0; k0 < 512; k0 += 16) {
        float4 av = *(const float4*)(A  + (size_t)(m0 + r)*512 + k0 + c*4);
        float4 bv = *(const float4*)(Wt + (size_t)(n0 + r)*512 + k0 + c*4);
        As[c*4+0][r] = av.x; As[c*4+1][r] = av.y; As[c*4+2][r] = av.z; As[c*4+3][r] = av.w;
        Bs[c*4+0][r] = bv.x; Bs[c*4+1][r] = bv.y; Bs[c*4+2][r] = bv.z; Bs[c*4+3][r] = bv.w;
        __syncthreads();
        #pragma unroll
        for (int kk = 0; kk < 16; ++kk) {
            float4 a4 = *(const float4*)(&As[kk][ty*4]);
            float4 b4 = *(const float4*)(&Bs[kk][tx*4]);
            float aa[4] = {a4.x, a4.y, a4.z, a4.w};
            float bb[4] = {b4.x, b4.y, b4.z, b4.w};
            #pragma unroll
            for (int i = 0; i < 4; ++i)
                #pragma unroll
                for (int j = 0; j < 4; ++j)
                    acc[i][j] += aa[i] * bb[j];
        }
        __syncthreads();
    }

    const int which = n0 >> 9;             // 0=q 1=k 2=v
    const int h = (n0 >> 6) & 7;
    const int d0 = tx * 4;
    float* dst = (which == 0) ? qd : (which == 1) ? kd : vd;
    #pragma unroll
    for (int i = 0; i < 4; ++i) {
        int m = m0 + ty*4 + i;
        int b = m >> 11, s = m & 2047;
        float4 o;
        o.x = acc[i][0] + bias[n0 + d0 + 0];
        o.y = acc[i][1] + bias[n0 + d0 + 1];
        o.z = acc[i][2] + bias[n0 + d0 + 2];
        o.w = acc[i][3] + bias[n0 + d0 + 3];
        *(float4*)(dst + (((size_t)(b*HH + h))*SS + s)*DH + d0) = o;
    }
}

// ---------------------------------------------------------------------------
// Banded attention, one (b, h, 32-row q-tile) per block.
// Key window [i0-128, i0+31+128] (<=288 keys) contains every row's full band
// -> exact softmax, no online rescale. Per-head band probs stored as bf16 in
// pb (reduced over heads by reduce_w); if pb==nullptr, atomicAdd into wout.
// ---------------------------------------------------------------------------
__global__ __launch_bounds__(512) void attn_ph(
    const float* __restrict__ qd, const float* __restrict__ kd,
    const float* __restrict__ vd, float* __restrict__ ctx,
    __hip_bfloat16* __restrict__ pb, float* __restrict__ wout)
{
    __shared__ float qs[32][DH];
    __shared__ float sc[32 * SW];

    const int tid = threadIdx.x;
    const int ti = blockIdx.x;
    const int b  = blockIdx.y;
    const int h  = blockIdx.z;
    const int i0 = ti * 32;
    const int jlo = (i0 - WW > 0) ? i0 - WW : 0;
    const int jhi = (i0 + 31 + WW < SS - 1) ? i0 + 31 + WW : SS - 1;
    const int nj = jhi - jlo + 1;          // <= 288

    const float* qbase = qd + ((size_t)(b*HH + h))*SS*DH;
    const float* kbase = kd + ((size_t)(b*HH + h))*SS*DH;
    const float* vbase = vd + ((size_t)(b*HH + h))*SS*DH;

    // stage Q tile: 512 threads x 1 float4 = 32x64
    {
        int row = tid >> 4, d4 = (tid & 15) * 4;
        *(float4*)(&qs[row][d4]) =
            *(const float4*)(qbase + (size_t)(i0 + row)*DH + d4);
    }
    __syncthreads();

    // ---- scores: thread owns one key column for 16 rows ----
    const int qh  = tid >> 8;              // row half 0/1
    const int jj0 = tid & 255;
    for (int jj = jj0; jj < nj; jj += 256) {
        const int j = jlo + jj;
        const float* krow = kbase + (size_t)j * DH;
        float s[16] = {};
        #pragma unroll
        for (int d4 = 0; d4 < DH; d4 += 4) {
            float4 kv = *(const float4*)(krow + d4);
            #pragma unroll
            for (int q2 = 0; q2 < 16; ++q2) {
                float4 qv = *(const float4*)(&qs[qh*16 + q2][d4]);
                s[q2] += qv.x*kv.x + qv.y*kv.y + qv.z*kv.z + qv.w*kv.w;
            }
        }
        #pragma unroll
        for (int q2 = 0; q2 < 16; ++q2) {
            int i = i0 + qh*16 + q2;
            int dd = i - j; if (dd < 0) dd = -dd;
            sc[(qh*16 + q2)*SW + jj] = (dd <= WW) ? s[q2] * 0.125f : -1e30f;
        }
    }
    __syncthreads();

    // ---- exact softmax: 16 threads per row ----
    const int qi   = tid >> 4;
    const int part = tid & 15;
    float mrow = -1e30f;
    #pragma unroll
    for (int t = 0; t < 18; ++t) {
        int jj = part + (t << 4);
        if (jj < nj) mrow = fmaxf(mrow, sc[qi*SW + jj]);
    }
    #pragma unroll
    for (int o = 1; o < 16; o <<= 1) mrow = fmaxf(mrow, __shfl_xor(mrow, o));

    float ssum = 0.f;
    float ev[18];
    #pragma unroll
    for (int t = 0; t < 18; ++t) {
        int jj = part + (t << 4);
        if (jj < nj) { float e = __expf(sc[qi*SW + jj] - mrow); ev[t] = e; ssum += e; }
        else ev[t] = 0.f;
    }
    #pragma unroll
    for (int o = 1; o < 16; o <<= 1) ssum += __shfl_xor(ssum, o);
    const float inv = 1.0f / ssum;

    if (pb != nullptr) {
        __hip_bfloat16* prow = pb + (((size_t)((b*HH + h)*NTILE + ti))*32 + qi)*PBW;
        #pragma unroll
        for (int t = 0; t < 18; ++t) {
            int jj = part + (t << 4);
            if (jj < nj) {
                float p = ev[t] * inv;
                sc[qi*SW + jj] = p;
                prow[jj] = __float2bfloat16(p);
            }
        }
    } else {
        float* wrow = wout + ((size_t)(b*SS + i0 + qi))*SS + jlo;
        #pragma unroll
        for (int t = 0; t < 18; ++t) {
            int jj = part + (t << 4);
            if (jj < nj) {
                float p = ev[t] * inv;
                sc[qi*SW + jj] = p;
                atomicAdd(wrow + jj, 0.125f * p);
            }
        }
    }
    __syncthreads();

    // ---- PV: thread owns (row qi, 4 dims) ----
    const int d0 = part * 4;
    float cacc[4] = {};
    for (int jj = 0; jj < nj; ++jj) {
        float p = sc[qi*SW + jj];
        float4 vv = *(const float4*)(vbase + (size_t)(jlo + jj)*DH + d0);
        cacc[0] += p*vv.x; cacc[1] += p*vv.y; cacc[2] += p*vv.z; cacc[3] += p*vv.w;
    }
    *(float4*)(ctx + ((size_t)(b*SS + i0 + qi))*EE + h*DH + d0) =
        make_float4(cacc[0], cacc[1], cacc[2], cacc[3]);
}

// ---------------------------------------------------------------------------
// Head-average reduce: wout[b, i, j] = 0.125 * sum_h pb[b,h,tile,row,jj]
// ---------------------------------------------------------------------------
__global__ __launch_bounds__(256) void reduce_w(
    const __hip_bfloat16* __restrict__ pb, float* __restrict__ wout)
{
    const int ti = blockIdx.x;
    const int b  = blockIdx.y;
    const int i0 = ti * 32;
    const int jlo = (i0 - WW > 0) ? i0 - WW : 0;
    const int jhi = (i0 + 31 + WW < SS - 1) ? i0 + 31 + WW : SS - 1;
    const int nj = jhi - jlo + 1;

    for (int qi = 0; qi < 32; ++qi) {
        float* wrow = wout + ((size_t)(b*SS + i0 + qi))*SS + jlo;
        for (int jj = threadIdx.x; jj < nj; jj += 256) {
            float s = 0.f;
            #pragma unroll
            for (int h = 0; h < HH; ++h)
                s += __bfloat162float(
                    pb[(((size_t)((b*HH + h)*NTILE + ti))*32 + qi)*PBW + jj]);
            wrow[jj] = 0.125f * s;
        }
    }
}

// ---------------------------------------------------------------------------
// Out-proj GEMM with fused per-tile column max (pooled partial)
// ---------------------------------------------------------------------------
__global__ __launch_bounds__(256) void out_gemm(
    const float* __restrict__ A, const float* __restrict__ Wt,
    const float* __restrict__ bias, float* __restrict__ part)
{
    __shared__ float As[16][64];
    __shared__ float Bs[16][64];
    __shared__ float red[16][64];
    const int tid = threadIdx.x;
    const int m0 = blockIdx.x * 64;
    const int n0 = blockIdx.y * 64;
    const int tx = tid & 15, ty = tid >> 4;
    const int r = tid >> 2, c = tid & 3;

    float acc[4][4] = {};
    for (int k0 = 0; k0 < 512; k0 += 16) {
        float4 av = *(const float4*)(A  + (size_t)(m0 + r)*512 + k0 + c*4);
        float4 bv = *(const float4*)(Wt + (size_t)(n0 + r)*512 + k0 + c*4);
        As[c*4+0][r] = av.x; As[c*4+1][r] = av.y; As[c*4+2][r] = av.z; As[c*4+3][r] = av.w;
        Bs[c*4+0][r] = bv.x; Bs[c*4+1][r] = bv.y; Bs[c*4+2][r] = bv.z; Bs[c*4+3][r] = bv.w;
        __syncthreads();
        #pragma unroll
        for (int kk = 0; kk < 16; ++kk) {
            float4 a4 = *(const float4*)(&As[kk][ty*4]);
            float4 b4 = *(const float4*)(&Bs[kk][tx*4]);
            float aa[4] = {a4.x, a4.y, a4.z, a4.w};
            float bb[4] = {b4.x, b4.y, b4.z, b4.w};
            #pragma unroll
            for (int i = 0; i < 4; ++i)
                #pragma unroll
                for (int j = 0; j < 4; ++j)
                    acc[i][j] += aa[i] * bb[j];
        }
        __syncthreads();
    }

    float lm[4] = {-1e30f, -1e30f, -1e30f, -1e30f};
    #pragma unroll
    for (int i = 0; i < 4; ++i)
        #pragma unroll
        for (int j = 0; j < 4; ++j)
            lm[j] = fmaxf(lm[j], acc[i][j]);
    #pragma unroll
    for (int j = 0; j < 4; ++j) red[ty][tx*4 + j] = lm[j];
    __syncthreads();
    if (tid < 64) {
        float m = red[0][tid];
        #pragma unroll
        for (int t = 1; t < 16; ++t) m = fmaxf(m, red[t][tid]);
        part[(size_t)blockIdx.x * EE + n0 + tid] = m + bias[n0 + tid];
    }
}

__global__ void pool_final(const float* __restrict__ part, float* __restrict__ pooled)
{
    int e = blockIdx.x * 256 + threadIdx.x;   // grid.x = 2
    int b = blockIdx.y;
    float m = -1e30f;
    #pragma unroll
    for (int t = 0; t < 32; ++t)
        m = fmaxf(m, part[((size_t)(b*32 + t))*EE + e]);
    pooled[b*EE + e] = m;
}

// ---------------------------------------------------------------------------
extern "C" void kernel_launch(void* const* d_in, const int* in_sizes, int n_in,
                              void* d_out, int out_size, void* d_ws, size_t ws_size,
                              hipStream_t stream)
{
    const float* emb = (const float*)d_in[0];
    const float* ipw = (const float*)d_in[1];
    const float* ipb = (const float*)d_in[2];
    const float* ow  = (const float*)d_in[3];
    const float* ob  = (const float*)d_in[4];

    float* pooled = (float*)d_out;                       // [4,512]
    float* wout   = pooled + (size_t)BB*EE;              // [4,2048,2048]

    const size_t headsz = (size_t)BB*HH*SS*DH;           // 4.19M floats
    float* q    = (float*)d_ws;
    float* k    = q + headsz;
    float* v    = k + headsz;
    float* ctx  = v + headsz;                            // [8192,512]
    float* part = ctx + (size_t)MM*EE;                   // [128,512]
    float* endf = part + 128*EE;

    const size_t pbElems = (size_t)BB*HH*NTILE*32*PBW;   // 18.87M
    const size_t baseBytes = (size_t)(endf - (float*)d_ws) * sizeof(float);
    __hip_bfloat16* pb = nullptr;
    if (ws_size >= baseBytes + pbElems * sizeof(__hip_bfloat16))
        pb = (__hip_bfloat16*)endf;

    hipMemsetAsync(wout, 0, (size_t)BB*SS*SS*sizeof(float), stream);
    qkv_gemm<<<dim3(128, 24), 256, 0, stream>>>(emb, ipw, ipb, q, k, v);
    attn_ph<<<dim3(NTILE, BB, HH), 512, 0, stream>>>(q, k, v, ctx, pb, wout);
    if (pb != nullptr)
        reduce_w<<<dim3(NTILE, BB), 256, 0, stream>>>(pb, wout);
    out_gemm<<<dim3(128, 8), 256, 0, stream>>>(ctx, ow, ob, part);
    pool_final<<<dim3(2, BB), 256, 0, stream>>>(part, pooled);
}

// Round 3
// 332.711 us; speedup vs baseline: 2.2906x; 2.2649x over previous
//
#include <hip/hip_runtime.h>
#include <math.h>

#define BB   4
#define SS   2048
#define EE   512
#define HH   8
#define DH   64
#define WW   128
#define MM   (BB*SS)      // 8192
#define NTILE (SS/32)     // 64 q-tiles per batch
#define SWH  296          // fp16 score stride (mult of 8 -> 16B-aligned b128 frags)
#define VTP  296          // fp16 V^T stride
#define SWW  289          // weights-kernel fp32 LDS stride

typedef _Float16 f16x8 __attribute__((ext_vector_type(8)));
typedef float    f32x4 __attribute__((ext_vector_type(4)));

// ---------------------------------------------------------------------------
// QKV GEMM (fp32 compute), epilogue converts to fp16 q/k/v [B,H,S,DH]
// ---------------------------------------------------------------------------
__global__ __launch_bounds__(256) void qkv_gemm(
    const float* __restrict__ A, const float* __restrict__ Wt,
    const float* __restrict__ bias,
    _Float16* __restrict__ qd, _Float16* __restrict__ kd, _Float16* __restrict__ vd)
{
    __shared__ float As[16][64];
    __shared__ float Bs[16][64];
    const int tid = threadIdx.x;
    const int m0 = blockIdx.x * 64;
    const int n0 = blockIdx.y * 64;
    const int tx = tid & 15, ty = tid >> 4;
    const int r = tid >> 2, c = tid & 3;

    float acc[4][4] = {};
    for (int k0 = 0; k0 < 512; k0 += 16) {
        float4 av = *(const float4*)(A  + (size_t)(m0 + r)*512 + k0 + c*4);
        float4 bv = *(const float4*)(Wt + (size_t)(n0 + r)*512 + k0 + c*4);
        As[c*4+0][r] = av.x; As[c*4+1][r] = av.y; As[c*4+2][r] = av.z; As[c*4+3][r] = av.w;
        Bs[c*4+0][r] = bv.x; Bs[c*4+1][r] = bv.y; Bs[c*4+2][r] = bv.z; Bs[c*4+3][r] = bv.w;
        __syncthreads();
        #pragma unroll
        for (int kk = 0; kk < 16; ++kk) {
            float4 a4 = *(const float4*)(&As[kk][ty*4]);
            float4 b4 = *(const float4*)(&Bs[kk][tx*4]);
            float aa[4] = {a4.x, a4.y, a4.z, a4.w};
            float bb[4] = {b4.x, b4.y, b4.z, b4.w};
            #pragma unroll
            for (int i = 0; i < 4; ++i)
                #pragma unroll
                for (int j = 0; j < 4; ++j)
                    acc[i][j] += aa[i] * bb[j];
        }
        __syncthreads();
    }

    const int which = n0 >> 9;             // 0=q 1=k 2=v
    const int h = (n0 >> 6) & 7;
    const int d0 = tx * 4;
    _Float16* dst = (which == 0) ? qd : (which == 1) ? kd : vd;
    union U4 { _Float16 h[4]; uint2 v; };
    #pragma unroll
    for (int i = 0; i < 4; ++i) {
        int m = m0 + ty*4 + i;
        int b = m >> 11, s = m & 2047;
        U4 u;
        u.h[0] = (_Float16)(acc[i][0] + bias[n0 + d0 + 0]);
        u.h[1] = (_Float16)(acc[i][1] + bias[n0 + d0 + 1]);
        u.h[2] = (_Float16)(acc[i][2] + bias[n0 + d0 + 2]);
        u.h[3] = (_Float16)(acc[i][3] + bias[n0 + d0 + 3]);
        *(uint2*)(dst + (((size_t)(b*HH + h))*SS + s)*DH + d0) = u.v;
    }
}

// ---------------------------------------------------------------------------
// MFMA banded attention: block=(b,h,ti), 512 thr = 8 waves.
// QK^T: wave w -> rowhalf=w&1, coltile group w>>1 (stride 4).
// PV:   wave w -> rowhalf=w&1, d-tile w>>1.
// Scores fp16 in LDS (fp32 softmax); V^T fp16 in LDS; (max,1/sum) -> stats.
// ---------------------------------------------------------------------------
__global__ __launch_bounds__(512, 4) void attn_mfma(
    const _Float16* __restrict__ qd, const _Float16* __restrict__ kd,
    const _Float16* __restrict__ vd, float* __restrict__ ctx,
    float2* __restrict__ stats)
{
    __shared__ _Float16 sc[32 * SWH];   // 18944 B
    __shared__ _Float16 vt[64 * VTP];   // 37888 B

    const int tid  = threadIdx.x;
    const int wid  = tid >> 6;
    const int lane = tid & 63;
    const int l15  = lane & 15;
    const int g    = lane >> 4;          // 0..3
    const int ti = blockIdx.x;
    const int b  = blockIdx.y;
    const int h  = blockIdx.z;
    const int i0 = ti * 32;
    const int jlo = (i0 - WW > 0) ? i0 - WW : 0;
    const int jhi = (i0 + 31 + WW < SS - 1) ? i0 + 31 + WW : SS - 1;
    const int nj = jhi - jlo + 1;        // <= 288
    const int NC = (nj + 15) >> 4;       // <= 18 col-tiles

    const _Float16* qb = qd + ((size_t)(b*HH + h))*SS*DH;
    const _Float16* kb = kd + ((size_t)(b*HH + h))*SS*DH;
    const _Float16* vb = vd + ((size_t)(b*HH + h))*SS*DH;

    // ---- stage V^T into LDS (zeros past jhi) ----
    for (int idx = tid; idx < 288*8; idx += 512) {
        int row = idx >> 3, d0 = (idx & 7) * 8;
        int j = jlo + row;
        f16x8 vv = {};
        if (j <= jhi) vv = *(const f16x8*)(vb + (size_t)j*DH + d0);
        #pragma unroll
        for (int e = 0; e < 8; ++e)
            vt[(d0 + e)*VTP + row] = vv[e];
    }

    // ---- QK^T via MFMA ----
    {
        const int rh = wid & 1, cgrp = wid >> 1;
        const int qrow = i0 + rh*16 + l15;
        f16x8 aq0 = *(const f16x8*)(qb + (size_t)qrow*DH +      g*8);
        f16x8 aq1 = *(const f16x8*)(qb + (size_t)qrow*DH + 32 + g*8);
        #pragma unroll
        for (int t = 0; t < 5; ++t) {
            int c = cgrp + t*4;
            if (c < NC) {
                int jj = c*16 + l15;
                int j  = jlo + jj;
                int jc = (j < SS) ? j : SS - 1;
                f16x8 bk0 = *(const f16x8*)(kb + (size_t)jc*DH +      g*8);
                f16x8 bk1 = *(const f16x8*)(kb + (size_t)jc*DH + 32 + g*8);
                f32x4 s = {0.f, 0.f, 0.f, 0.f};
                s = __builtin_amdgcn_mfma_f32_16x16x32_f16(aq0, bk0, s, 0, 0, 0);
                s = __builtin_amdgcn_mfma_f32_16x16x32_f16(aq1, bk1, s, 0, 0, 0);
                #pragma unroll
                for (int r = 0; r < 4; ++r) {
                    int srow = rh*16 + g*4 + r;
                    int i = i0 + srow;
                    int dd = i - j; if (dd < 0) dd = -dd;
                    float val = (dd <= WW && j < SS) ? s[r]*0.125f : -60000.f;
                    sc[srow*SWH + jj] = (_Float16)val;
                }
            }
        }
    }
    __syncthreads();

    // ---- exact softmax: 16 threads / row, fp32 math ----
    {
        const int qi = tid >> 4, pt = tid & 15;
        float mrow = -1e30f;
        #pragma unroll
        for (int t = 0; t < 18; ++t) {
            int jj = pt + (t << 4);
            if (jj < nj) mrow = fmaxf(mrow, (float)sc[qi*SWH + jj]);
        }
        #pragma unroll
        for (int o = 1; o < 16; o <<= 1) mrow = fmaxf(mrow, __shfl_xor(mrow, o));

        float ssum = 0.f;
        float ev[18];
        #pragma unroll
        for (int t = 0; t < 18; ++t) {
            int jj = pt + (t << 4);
            if (jj < nj) { float e = __expf((float)sc[qi*SWH + jj] - mrow); ev[t] = e; ssum += e; }
            else ev[t] = 0.f;
        }
        #pragma unroll
        for (int o = 1; o < 16; o <<= 1) ssum += __shfl_xor(ssum, o);
        const float inv = 1.0f / ssum;

        #pragma unroll
        for (int t = 0; t < 18; ++t) {          // unconditional: zeros fill [nj,288)
            int jj = pt + (t << 4);
            sc[qi*SWH + jj] = (_Float16)(ev[t] * inv);
        }
        if (pt == 0)
            stats[((size_t)(b*HH + h))*SS + i0 + qi] = make_float2(mrow, inv);
    }
    __syncthreads();

    // ---- PV via MFMA: wave -> (rowhalf, d-tile), K-loop 9 x 32 keys ----
    {
        const int rh = wid & 1, dt = wid >> 1;
        f32x4 acc = {0.f, 0.f, 0.f, 0.f};
        #pragma unroll
        for (int ks = 0; ks < 9; ++ks) {
            f16x8 ap = *(const f16x8*)&sc[(rh*16 + l15)*SWH + ks*32 + g*8];
            f16x8 bv = *(const f16x8*)&vt[(dt*16 + l15)*VTP + ks*32 + g*8];
            acc = __builtin_amdgcn_mfma_f32_16x16x32_f16(ap, bv, acc, 0, 0, 0);
        }
        #pragma unroll
        for (int r = 0; r < 4; ++r) {
            int row = i0 + rh*16 + g*4 + r;
            ctx[((size_t)(b*SS + row))*EE + h*DH + dt*16 + l15] = acc[r];
        }
    }
}

// ---------------------------------------------------------------------------
// Weights: block=(b,ti). Recompute QK^T per head via MFMA, p from stats,
// head-mean in regs -> LDS -> write FULL 2048-wide rows (zeros included).
// ---------------------------------------------------------------------------
__global__ __launch_bounds__(512, 4) void weights_k(
    const _Float16* __restrict__ qd, const _Float16* __restrict__ kd,
    const float2* __restrict__ stats, float* __restrict__ wout)
{
    __shared__ float wacc[32 * SWW];    // 36992 B

    const int tid  = threadIdx.x;
    const int wid  = tid >> 6;
    const int lane = tid & 63;
    const int l15  = lane & 15;
    const int g    = lane >> 4;
    const int ti = blockIdx.x;
    const int b  = blockIdx.y;
    const int i0 = ti * 32;
    const int jlo = (i0 - WW > 0) ? i0 - WW : 0;
    const int jhi = (i0 + 31 + WW < SS - 1) ? i0 + 31 + WW : SS - 1;
    const int nj = jhi - jlo + 1;
    const int NC = (nj + 15) >> 4;

    const int rh = wid & 1, cgrp = wid >> 1;
    const int qrow = i0 + rh*16 + l15;

    float ws[5][4];
    #pragma unroll
    for (int t = 0; t < 5; ++t)
        #pragma unroll
        for (int r = 0; r < 4; ++r) ws[t][r] = 0.f;

    for (int h = 0; h < HH; ++h) {
        const _Float16* qb = qd + ((size_t)(b*HH + h))*SS*DH;
        const _Float16* kb = kd + ((size_t)(b*HH + h))*SS*DH;
        f16x8 aq0 = *(const f16x8*)(qb + (size_t)qrow*DH +      g*8);
        f16x8 aq1 = *(const f16x8*)(qb + (size_t)qrow*DH + 32 + g*8);
        float2 st[4];
        #pragma unroll
        for (int r = 0; r < 4; ++r)
            st[r] = stats[((size_t)(b*HH + h))*SS + i0 + rh*16 + g*4 + r];

        #pragma unroll
        for (int t = 0; t < 5; ++t) {
            int c = cgrp + t*4;
            if (c < NC) {
                int jj = c*16 + l15;
                int j  = jlo + jj;
                int jc = (j < SS) ? j : SS - 1;
                f16x8 bk0 = *(const f16x8*)(kb + (size_t)jc*DH +      g*8);
                f16x8 bk1 = *(const f16x8*)(kb + (size_t)jc*DH + 32 + g*8);
                f32x4 s = {0.f, 0.f, 0.f, 0.f};
                s = __builtin_amdgcn_mfma_f32_16x16x32_f16(aq0, bk0, s, 0, 0, 0);
                s = __builtin_amdgcn_mfma_f32_16x16x32_f16(aq1, bk1, s, 0, 0, 0);
                #pragma unroll
                for (int r = 0; r < 4; ++r) {
                    int i = i0 + rh*16 + g*4 + r;
                    int dd = i - j; if (dd < 0) dd = -dd;
                    if (dd <= WW && j < SS)
                        ws[t][r] += __expf(s[r]*0.125f - st[r].x) * st[r].y;
                }
            }
        }
    }

    // deposit per-wave accumulators (disjoint positions across waves)
    #pragma unroll
    for (int t = 0; t < 5; ++t) {
        int c = cgrp + t*4;
        if (c < NC) {
            #pragma unroll
            for (int r = 0; r < 4; ++r)
                wacc[(rh*16 + g*4 + r)*SWW + c*16 + l15] = ws[t][r];
        }
    }
    __syncthreads();

    // write full rows: 16 threads/row, 128 cols each, float4 stores
    {
        const int row = tid >> 4, pt = tid & 15;
        const int i = i0 + row;
        const int blo = (i - WW > 0) ? i - WW : 0;
        const int bhi = (i + WW < SS - 1) ? i + WW : SS - 1;
        float* wrow = wout + ((size_t)(b*SS + i))*SS;
        for (int j4 = pt*128; j4 < pt*128 + 128; j4 += 4) {
            float4 o;
            float* oo = (float*)&o;
            #pragma unroll
            for (int e = 0; e < 4; ++e) {
                int j = j4 + e;
                oo[e] = (j >= blo && j <= bhi) ? wacc[row*SWW + (j - jlo)] * 0.125f : 0.f;
            }
            *(float4*)(wrow + j4) = o;
        }
    }
}

// ---------------------------------------------------------------------------
// Out-proj GEMM with fused per-tile column max (pooled partial)
// ---------------------------------------------------------------------------
__global__ __launch_bounds__(256) void out_gemm(
    const float* __restrict__ A, const float* __restrict__ Wt,
    const float* __restrict__ bias, float* __restrict__ part)
{
    __shared__ float As[16][64];
    __shared__ float Bs[16][64];
    __shared__ float red[16][64];
    const int tid = threadIdx.x;
    const int m0 = blockIdx.x * 64;
    const int n0 = blockIdx.y * 64;
    const int tx = tid & 15, ty = tid >> 4;
    const int r = tid >> 2, c = tid & 3;

    float acc[4][4] = {};
    for (int k0 = 0; k0 < 512; k0 += 16) {
        float4 av = *(const float4*)(A  + (size_t)(m0 + r)*512 + k0 + c*4);
        float4 bv = *(const float4*)(Wt + (size_t)(n0 + r)*512 + k0 + c*4);
        As[c*4+0][r] = av.x; As[c*4+1][r] = av.y; As[c*4+2][r] = av.z; As[c*4+3][r] = av.w;
        Bs[c*4+0][r] = bv.x; Bs[c*4+1][r] = bv.y; Bs[c*4+2][r] = bv.z; Bs[c*4+3][r] = bv.w;
        __syncthreads();
        #pragma unroll
        for (int kk = 0; kk < 16; ++kk) {
            float4 a4 = *(const float4*)(&As[kk][ty*4]);
            float4 b4 = *(const float4*)(&Bs[kk][tx*4]);
            float aa[4] = {a4.x, a4.y, a4.z, a4.w};
            float bb[4] = {b4.x, b4.y, b4.z, b4.w};
            #pragma unroll
            for (int i = 0; i < 4; ++i)
                #pragma unroll
                for (int j = 0; j < 4; ++j)
                    acc[i][j] += aa[i] * bb[j];
        }
        __syncthreads();
    }

    float lm[4] = {-1e30f, -1e30f, -1e30f, -1e30f};
    #pragma unroll
    for (int i = 0; i < 4; ++i)
        #pragma unroll
        for (int j = 0; j < 4; ++j)
            lm[j] = fmaxf(lm[j], acc[i][j]);
    #pragma unroll
    for (int j = 0; j < 4; ++j) red[ty][tx*4 + j] = lm[j];
    __syncthreads();
    if (tid < 64) {
        float m = red[0][tid];
        #pragma unroll
        for (int t = 1; t < 16; ++t) m = fmaxf(m, red[t][tid]);
        part[(size_t)blockIdx.x * EE + n0 + tid] = m + bias[n0 + tid];
    }
}

__global__ void pool_final(const float* __restrict__ part, float* __restrict__ pooled)
{
    int e = blockIdx.x * 256 + threadIdx.x;   // grid.x = 2
    int b = blockIdx.y;
    float m = -1e30f;
    #pragma unroll
    for (int t = 0; t < 32; ++t)
        m = fmaxf(m, part[((size_t)(b*32 + t))*EE + e]);
    pooled[b*EE + e] = m;
}

// ---------------------------------------------------------------------------
extern "C" void kernel_launch(void* const* d_in, const int* in_sizes, int n_in,
                              void* d_out, int out_size, void* d_ws, size_t ws_size,
                              hipStream_t stream)
{
    const float* emb = (const float*)d_in[0];
    const float* ipw = (const float*)d_in[1];
    const float* ipb = (const float*)d_in[2];
    const float* ow  = (const float*)d_in[3];
    const float* ob  = (const float*)d_in[4];

    float* pooled = (float*)d_out;                       // [4,512]
    float* wout   = pooled + (size_t)BB*EE;              // [4,2048,2048]

    const size_t headsz = (size_t)BB*HH*SS*DH;           // 4,194,304 elems
    _Float16* q = (_Float16*)d_ws;
    _Float16* k = q + headsz;
    _Float16* v = k + headsz;
    float* ctx   = (float*)(v + headsz);                 // [8192,512] fp32
    float* part  = ctx + (size_t)MM*EE;                  // [128,512]
    float2* stats = (float2*)(part + 128*EE);            // [4,8,2048]

    qkv_gemm<<<dim3(128, 24), 256, 0, stream>>>(emb, ipw, ipb, q, k, v);
    attn_mfma<<<dim3(NTILE, BB, HH), 512, 0, stream>>>(q, k, v, ctx, stats);
    weights_k<<<dim3(NTILE, BB), 512, 0, stream>>>(q, k, stats, wout);
    out_gemm<<<dim3(128, 8), 256, 0, stream>>>(ctx, ow, ob, part);
    pool_final<<<dim3(2, BB), 256, 0, stream>>>(part, pooled);
}

// Round 4
// 140.957 us; speedup vs baseline: 5.4068x; 2.3604x over previous
//
#include <hip/hip_runtime.h>
#include <math.h>

#define BB   4
#define SS   2048
#define EE   512
#define HH   8
#define DH   64
#define WW   128
#define MM   (BB*SS)      // 8192
#define NTILE (SS/32)     // 64 q-tiles per batch
#define SWH  296          // fp16 score stride (mult of 8 -> 16B-aligned b128 frags)
#define VTP  296          // fp16 V^T stride
#define SWW  289          // weights-kernel fp32 LDS stride
#define LST  40           // GEMM LDS tile stride in halves (80B = 5*16B aligned)

typedef _Float16 f16x8 __attribute__((ext_vector_type(8)));
typedef float    f32x4 __attribute__((ext_vector_type(4)));

// ---------------------------------------------------------------------------
// fp32 -> fp16 conversion for emb / in_proj_w / out_w (float4 -> 4x fp16)
// ---------------------------------------------------------------------------
__global__ __launch_bounds__(256) void convert3(
    const float* __restrict__ a, const float* __restrict__ bsrc,
    const float* __restrict__ c,
    _Float16* __restrict__ da, _Float16* __restrict__ db, _Float16* __restrict__ dc)
{
    const size_t na4 = (size_t)MM*EE/4;        // 1,048,576
    const size_t nb4 = (size_t)3*EE*EE/4;      // 196,608
    const size_t nc4 = (size_t)EE*EE/4;        // 65,536
    const size_t tot = na4 + nb4 + nc4;
    for (size_t i = (size_t)blockIdx.x*256 + threadIdx.x; i < tot;
         i += (size_t)gridDim.x*256) {
        const float* s; _Float16* d; size_t off;
        if (i < na4)            { s = a;    d = da; off = i; }
        else if (i < na4 + nb4) { s = bsrc; d = db; off = i - na4; }
        else                    { s = c;    d = dc; off = i - na4 - nb4; }
        float4 v = ((const float4*)s)[off];
        union { _Float16 h[4]; uint2 u; } o;
        o.h[0] = (_Float16)v.x; o.h[1] = (_Float16)v.y;
        o.h[2] = (_Float16)v.z; o.h[3] = (_Float16)v.w;
        ((uint2*)d)[off] = o.u;
    }
}

// ---------------------------------------------------------------------------
// QKV MFMA GEMM: C[m,n] = A16[m,:]
//  . W16[n,:] + bias[n]; scatter fp16 into q/k/v
// 128x128 tile, BK=32, 256 thr = 4 waves (2x2), wave does 64x64.
// ---------------------------------------------------------------------------
__global__ __launch_bounds__(256) void qkv_mfma(
    const _Float16* __restrict__ A, const _Float16* __restrict__ Wt,
    const float* __restrict__ bias,
    _Float16* __restrict__ qd, _Float16* __restrict__ kd, _Float16* __restrict__ vd)
{
    __shared__ _Float16 As[128*LST];
    __shared__ _Float16 Bs[128*LST];

    const int tid = threadIdx.x;
    const int wid = tid >> 6, lane = tid & 63;
    const int l15 = lane & 15, g = lane >> 4;
    const int wr = wid >> 1, wc = wid & 1;
    const int m0 = blockIdx.x * 128;
    const int n0 = blockIdx.y * 128;
    const int r = tid >> 2, c = tid & 3;

    f32x4 acc[4][4] = {};
    for (int k0 = 0; k0 < 512; k0 += 32) {
        f16x8 av0 = *(const f16x8*)(A  + (size_t)(m0 + r)*512      + k0 + c*8);
        f16x8 av1 = *(const f16x8*)(A  + (size_t)(m0 + r + 64)*512 + k0 + c*8);
        f16x8 bv0 = *(const f16x8*)(Wt + (size_t)(n0 + r)*512      + k0 + c*8);
        f16x8 bv1 = *(const f16x8*)(Wt + (size_t)(n0 + r + 64)*512 + k0 + c*8);
        __syncthreads();
        *(f16x8*)(&As[r*LST + c*8])        = av0;
        *(f16x8*)(&As[(r + 64)*LST + c*8]) = av1;
        *(f16x8*)(&Bs[r*LST + c*8])        = bv0;
        *(f16x8*)(&Bs[(r + 64)*LST + c*8]) = bv1;
        __syncthreads();
        f16x8 af[4], bf[4];
        #pragma unroll
        for (int f = 0; f < 4; ++f) {
            af[f] = *(const f16x8*)(&As[(wr*64 + f*16 + l15)*LST + g*8]);
            bf[f] = *(const f16x8*)(&Bs[(wc*64 + f*16 + l15)*LST + g*8]);
        }
        #pragma unroll
        for (int fi = 0; fi < 4; ++fi)
            #pragma unroll
            for (int fj = 0; fj < 4; ++fj)
                acc[fi][fj] = __builtin_amdgcn_mfma_f32_16x16x32_f16(
                    af[fi], bf[fj], acc[fi][fj], 0, 0, 0);
    }

    // epilogue: scatter fp16 into q/k/v [B,H,S,64]
    const int which = n0 >> 9;
    _Float16* dst = (which == 0) ? qd : (which == 1) ? kd : vd;
    #pragma unroll
    for (int fj = 0; fj < 4; ++fj) {
        const int col = n0 + wc*64 + fj*16 + l15;
        const int h = (col >> 6) & 7;
        const int d = fj*16 + l15 + (wc*64 & 63); // = (col & 63)
        const float bc = bias[col];
        #pragma unroll
        for (int fi = 0; fi < 4; ++fi)
            #pragma unroll
            for (int rr = 0; rr < 4; ++rr) {
                int grow = m0 + wr*64 + fi*16 + g*4 + rr;
                int b = grow >> 11, s = grow & 2047;
                dst[(((size_t)(b*HH + h))*SS + s)*DH + (col & 63)] =
                    (_Float16)(acc[fi][fj][rr] + bc);
            }
    }
}

// ---------------------------------------------------------------------------
// Out-proj MFMA GEMM + fused per-column max over the 128-row tile.
// part[rowtile, n] = max_rows(ctx @ ow^T)[.., n] + ob[n]
// ---------------------------------------------------------------------------
__global__ __launch_bounds__(256) void out_mfma(
    const _Float16* __restrict__ A, const _Float16* __restrict__ Wt,
    const float* __restrict__ bias, float* __restrict__ part)
{
    __shared__ _Float16 As[128*LST];
    __shared__ _Float16 Bs[128*LST];

    const int tid = threadIdx.x;
    const int wid = tid >> 6, lane = tid & 63;
    const int l15 = lane & 15, g = lane >> 4;
    const int wr = wid >> 1, wc = wid & 1;
    const int m0 = blockIdx.x * 128;
    const int n0 = blockIdx.y * 128;
    const int r = tid >> 2, c = tid & 3;

    f32x4 acc[4][4] = {};
    for (int k0 = 0; k0 < 512; k0 += 32) {
        f16x8 av0 = *(const f16x8*)(A  + (size_t)(m0 + r)*512      + k0 + c*8);
        f16x8 av1 = *(const f16x8*)(A  + (size_t)(m0 + r + 64)*512 + k0 + c*8);
        f16x8 bv0 = *(const f16x8*)(Wt + (size_t)(n0 + r)*512      + k0 + c*8);
        f16x8 bv1 = *(const f16x8*)(Wt + (size_t)(n0 + r + 64)*512 + k0 + c*8);
        __syncthreads();
        *(f16x8*)(&As[r*LST + c*8])        = av0;
        *(f16x8*)(&As[(r + 64)*LST + c*8]) = av1;
        *(f16x8*)(&Bs[r*LST + c*8])        = bv0;
        *(f16x8*)(&Bs[(r + 64)*LST + c*8]) = bv1;
        __syncthreads();
        f16x8 af[4], bf[4];
        #pragma unroll
        for (int f = 0; f < 4; ++f) {
            af[f] = *(const f16x8*)(&As[(wr*64 + f*16 + l15)*LST + g*8]);
            bf[f] = *(const f16x8*)(&Bs[(wc*64 + f*16 + l15)*LST + g*8]);
        }
        #pragma unroll
        for (int fi = 0; fi < 4; ++fi)
            #pragma unroll
            for (int fj = 0; fj < 4; ++fj)
                acc[fi][fj] = __builtin_amdgcn_mfma_f32_16x16x32_f16(
                    af[fi], bf[fj], acc[fi][fj], 0, 0, 0);
    }

    __syncthreads();                       // before reusing As as reduce buffer
    float* red = (float*)As;               // [2][128]
    #pragma unroll
    for (int fj = 0; fj < 4; ++fj) {
        float cm = -1e30f;
        #pragma unroll
        for (int fi = 0; fi < 4; ++fi)
            #pragma unroll
            for (int rr = 0; rr < 4; ++rr)
                cm = fmaxf(cm, acc[fi][fj][rr]);
        cm = fmaxf(cm, __shfl_xor(cm, 16));
        cm = fmaxf(cm, __shfl_xor(cm, 32));
        if (g == 0) red[wr*128 + wc*64 + fj*16 + l15] = cm;
    }
    __syncthreads();
    if (tid < 128) {
        float m = fmaxf(red[tid], red[128 + tid]) + bias[n0 + tid];
        part[(size_t)blockIdx.x * EE + n0 + tid] = m;
    }
}

// ---------------------------------------------------------------------------
// MFMA banded attention (unchanged from R3 except ctx is fp16 now)
// ---------------------------------------------------------------------------
__global__ __launch_bounds__(512, 4) void attn_mfma(
    const _Float16* __restrict__ qd, const _Float16* __restrict__ kd,
    const _Float16* __restrict__ vd, _Float16* __restrict__ ctx,
    float2* __restrict__ stats)
{
    __shared__ _Float16 sc[32 * SWH];   // 18944 B
    __shared__ _Float16 vt[64 * VTP];   // 37888 B

    const int tid  = threadIdx.x;
    const int wid  = tid >> 6;
    const int lane = tid & 63;
    const int l15  = lane & 15;
    const int g    = lane >> 4;
    const int ti = blockIdx.x;
    const int b  = blockIdx.y;
    const int h  = blockIdx.z;
    const int i0 = ti * 32;
    const int jlo = (i0 - WW > 0) ? i0 - WW : 0;
    const int jhi = (i0 + 31 + WW < SS - 1) ? i0 + 31 + WW : SS - 1;
    const int nj = jhi - jlo + 1;
    const int NC = (nj + 15) >> 4;

    const _Float16* qb = qd + ((size_t)(b*HH + h))*SS*DH;
    const _Float16* kb = kd + ((size_t)(b*HH + h))*SS*DH;
    const _Float16* vb = vd + ((size_t)(b*HH + h))*SS*DH;

    for (int idx = tid; idx < 288*8; idx += 512) {
        int row = idx >> 3, d0 = (idx & 7) * 8;
        int j = jlo + row;
        f16x8 vv = {};
        if (j <= jhi) vv = *(const f16x8*)(vb + (size_t)j*DH + d0);
        #pragma unroll
        for (int e = 0; e < 8; ++e)
            vt[(d0 + e)*VTP + row] = vv[e];
    }

    {
        const int rh = wid & 1, cgrp = wid >> 1;
        const int qrow = i0 + rh*16 + l15;
        f16x8 aq0 = *(const f16x8*)(qb + (size_t)qrow*DH +      g*8);
        f16x8 aq1 = *(const f16x8*)(qb + (size_t)qrow*DH + 32 + g*8);
        #pragma unroll
        for (int t = 0; t < 5; ++t) {
            int c = cgrp + t*4;
            if (c < NC) {
                int jj = c*16 + l15;
                int j  = jlo + jj;
                int jc = (j < SS) ? j : SS - 1;
                f16x8 bk0 = *(const f16x8*)(kb + (size_t)jc*DH +      g*8);
                f16x8 bk1 = *(const f16x8*)(kb + (size_t)jc*DH + 32 + g*8);
                f32x4 s = {0.f, 0.f, 0.f, 0.f};
                s = __builtin_amdgcn_mfma_f32_16x16x32_f16(aq0, bk0, s, 0, 0, 0);
                s = __builtin_amdgcn_mfma_f32_16x16x32_f16(aq1, bk1, s, 0, 0, 0);
                #pragma unroll
                for (int r = 0; r < 4; ++r) {
                    int srow = rh*16 + g*4 + r;
                    int i = i0 + srow;
                    int dd = i - j; if (dd < 0) dd = -dd;
                    float val = (dd <= WW && j < SS) ? s[r]*0.125f : -60000.f;
                    sc[srow*SWH + jj] = (_Float16)val;
                }
            }
        }
    }
    __syncthreads();

    {
        const int qi = tid >> 4, pt = tid & 15;
        float mrow = -1e30f;
        #pragma unroll
        for (int t = 0; t < 18; ++t) {
            int jj = pt + (t << 4);
            if (jj < nj) mrow = fmaxf(mrow, (float)sc[qi*SWH + jj]);
        }
        #pragma unroll
        for (int o = 1; o < 16; o <<= 1) mrow = fmaxf(mrow, __shfl_xor(mrow, o));

        float ssum = 0.f;
        float ev[18];
        #pragma unroll
        for (int t = 0; t < 18; ++t) {
            int jj = pt + (t << 4);
            if (jj < nj) { float e = __expf((float)sc[qi*SWH + jj] - mrow); ev[t] = e; ssum += e; }
            else ev[t] = 0.f;
        }
        #pragma unroll
        for (int o = 1; o < 16; o <<= 1) ssum += __shfl_xor(ssum, o);
        const float inv = 1.0f / ssum;

        #pragma unroll
        for (int t = 0; t < 18; ++t) {
            int jj = pt + (t << 4);
            sc[qi*SWH + jj] = (_Float16)(ev[t] * inv);
        }
        if (pt == 0)
            stats[((size_t)(b*HH + h))*SS + i0 + qi] = make_float2(mrow, inv);
    }
    __syncthreads();

    {
        const int rh = wid & 1, dt = wid >> 1;
        f32x4 acc = {0.f, 0.f, 0.f, 0.f};
        #pragma unroll
        for (int ks = 0; ks < 9; ++ks) {
            f16x8 ap = *(const f16x8*)&sc[(rh*16 + l15)*SWH + ks*32 + g*8];
            f16x8 bv = *(const f16x8*)&vt[(dt*16 + l15)*VTP + ks*32 + g*8];
            acc = __builtin_amdgcn_mfma_f32_16x16x32_f16(ap, bv, acc, 0, 0, 0);
        }
        #pragma unroll
        for (int r = 0; r < 4; ++r) {
            int row = i0 + rh*16 + g*4 + r;
            ctx[((size_t)(b*SS + row))*EE + h*DH + dt*16 + l15] = (_Float16)acc[r];
        }
    }
}

// ---------------------------------------------------------------------------
// Weights: recompute QK^T per head via MFMA, p from stats, head-mean ->
// write FULL 2048-wide rows (zeros included).
// ---------------------------------------------------------------------------
__global__ __launch_bounds__(512, 4) void weights_k(
    const _Float16* __restrict__ qd, const _Float16* __restrict__ kd,
    const float2* __restrict__ stats, float* __restrict__ wout)
{
    __shared__ float wacc[32 * SWW];    // 36992 B

    const int tid  = threadIdx.x;
    const int wid  = tid >> 6;
    const int lane = tid & 63;
    const int l15  = lane & 15;
    const int g    = lane >> 4;
    const int ti = blockIdx.x;
    const int b  = blockIdx.y;
    const int i0 = ti * 32;
    const int jlo = (i0 - WW > 0) ? i0 - WW : 0;
    const int jhi = (i0 + 31 + WW < SS - 1) ? i0 + 31 + WW : SS - 1;
    const int nj = jhi - jlo + 1;
    const int NC = (nj + 15) >> 4;

    const int rh = wid & 1, cgrp = wid >> 1;
    const int qrow = i0 + rh*16 + l15;

    float ws[5][4];
    #pragma unroll
    for (int t = 0; t < 5; ++t)
        #pragma unroll
        for (int r = 0; r < 4; ++r) ws[t][r] = 0.f;

    for (int h = 0; h < HH; ++h) {
        const _Float16* qb = qd + ((size_t)(b*HH + h))*SS*DH;
        const _Float16* kb = kd + ((size_t)(b*HH + h))*SS*DH;
        f16x8 aq0 = *(const f16x8*)(qb + (size_t)qrow*DH +      g*8);
        f16x8 aq1 = *(const f16x8*)(qb + (size_t)qrow*DH + 32 + g*8);
        float2 st[4];
        #pragma unroll
        for (int r = 0; r < 4; ++r)
            st[r] = stats[((size_t)(b*HH + h))*SS + i0 + rh*16 + g*4 + r];

        #pragma unroll
        for (int t = 0; t < 5; ++t) {
            int c = cgrp + t*4;
            if (c < NC) {
                int jj = c*16 + l15;
                int j  = jlo + jj;
                int jc = (j < SS) ? j : SS - 1;
                f16x8 bk0 = *(const f16x8*)(kb + (size_t)jc*DH +      g*8);
                f16x8 bk1 = *(const f16x8*)(kb + (size_t)jc*DH + 32 + g*8);
                f32x4 s = {0.f, 0.f, 0.f, 0.f};
                s = __builtin_amdgcn_mfma_f32_16x16x32_f16(aq0, bk0, s, 0, 0, 0);
                s = __builtin_amdgcn_mfma_f32_16x16x32_f16(aq1, bk1, s, 0, 0, 0);
                #pragma unroll
                for (int r = 0; r < 4; ++r) {
                    int i = i0 + rh*16 + g*4 + r;
                    int dd = i - j; if (dd < 0) dd = -dd;
                    if (dd <= WW && j < SS)
                        ws[t][r] += __expf(s[r]*0.125f - st[r].x) * st[r].y;
                }
            }
        }
    }

    #pragma unroll
    for (int t = 0; t < 5; ++t) {
        int c = cgrp + t*4;
        if (c < NC) {
            #pragma unroll
            for (int r = 0; r < 4; ++r)
                wacc[(rh*16 + g*4 + r)*SWW + c*16 + l15] = ws[t][r];
        }
    }
    __syncthreads();

    {
        const int row = tid >> 4, pt = tid & 15;
        const int i = i0 + row;
        const int blo = (i - WW > 0) ? i - WW : 0;
        const int bhi = (i + WW < SS - 1) ? i + WW : SS - 1;
        float* wrow = wout + ((size_t)(b*SS + i))*SS;
        for (int j4 = pt*128; j4 < pt*128 + 128; j4 += 4) {
            float4 o;
            float* oo = (float*)&o;
            #pragma unroll
            for (int e = 0; e < 4; ++e) {
                int j = j4 + e;
                oo[e] = (j >= blo && j <= bhi) ? wacc[row*SWW + (j - jlo)] * 0.125f : 0.f;
            }
            *(float4*)(wrow + j4) = o;
        }
    }
}

__global__ void pool_final(const float* __restrict__ part, float* __restrict__ pooled)
{
    int e = blockIdx.x * 256 + threadIdx.x;   // grid.x = 2
    int b = blockIdx.y;
    float m = -1e30f;
    #pragma unroll
    for (int t = 0; t < 16; ++t)
        m = fmaxf(m, part[((size_t)(b*16 + t))*EE + e]);
    pooled[b*EE + e] = m;
}

// ---------------------------------------------------------------------------
extern "C" void kernel_launch(void* const* d_in, const int* in_sizes, int n_in,
                              void* d_out, int out_size, void* d_ws, size_t ws_size,
                              hipStream_t stream)
{
    const float* emb = (const float*)d_in[0];
    const float* ipw = (const float*)d_in[1];
    const float* ipb = (const float*)d_in[2];
    const float* ow  = (const float*)d_in[3];
    const float* ob  = (const float*)d_in[4];

    float* pooled = (float*)d_out;                       // [4,512]
    float* wout   = pooled + (size_t)BB*EE;              // [4,2048,2048]

    const size_t headsz = (size_t)BB*HH*SS*DH;           // 4,194,304 elems
    _Float16* q    = (_Float16*)d_ws;
    _Float16* k    = q + headsz;
    _Float16* v    = k + headsz;
    _Float16* ctx  = v + headsz;                         // [8192,512] fp16
    _Float16* A16  = ctx + (size_t)MM*EE;                // emb fp16
    _Float16* W16  = A16 + (size_t)MM*EE;                // in_proj_w fp16
    _Float16* OW16 = W16 + (size_t)3*EE*EE;              // out_w fp16
    float* part    = (float*)(OW16 + (size_t)EE*EE);     // [64,512]
    float2* stats  = (float2*)(part + 64*EE);            // [4,8,2048]

    convert3<<<1280, 256, 0, stream>>>(emb, ipw, ow, A16, W16, OW16);
    qkv_mfma<<<dim3(64, 12), 256, 0, stream>>>(A16, W16, ipb, q, k, v);
    attn_mfma<<<dim3(NTILE, BB, HH), 512, 0, stream>>>(q, k, v, ctx, stats);
    weights_k<<<dim3(NTILE, BB), 512, 0, stream>>>(q, k, stats, wout);
    out_mfma<<<dim3(64, 4), 256, 0, stream>>>(ctx, OW16, ob, part);
    pool_final<<<dim3(2, BB), 256, 0, stream>>>(part, pooled);
}

// Round 6
// 125.332 us; speedup vs baseline: 6.0808x; 1.1247x over previous
//
#include <hip/hip_runtime.h>
#include <math.h>

#define BB   4
#define SS   2048
#define EE   512
#define HH   8
#define DH   64
#define WW   128
#define MM   (BB*SS)      // 8192
#define NTILE (SS/32)     // 64 q-tiles per batch
#define SWH  296          // fp16 score stride (mult of 8 -> 16B-aligned b128 frags)
#define VTP  296          // fp16 V^T stride (swizzled cols stay < 288)
#define WST  97           // weights-kernel fp32 LDS stride (96 cols + 1 pad)
#define LST  40           // GEMM LDS tile stride in halves (80B)

typedef _Float16 f16x8 __attribute__((ext_vector_type(8)));
typedef _Float16 f16x2 __attribute__((ext_vector_type(2)));
typedef float    f32x4 __attribute__((ext_vector_type(4)));

// ---------------------------------------------------------------------------
// fp32 -> fp16 conversion for emb / in_proj_w / out_w
// ---------------------------------------------------------------------------
__global__ __launch_bounds__(256) void convert3(
    const float* __restrict__ a, const float* __restrict__ bsrc,
    const float* __restrict__ c,
    _Float16* __restrict__ da, _Float16* __restrict__ db, _Float16* __restrict__ dc)
{
    const size_t na4 = (size_t)MM*EE/4;
    const size_t nb4 = (size_t)3*EE*EE/4;
    const size_t nc4 = (size_t)EE*EE/4;
    const size_t tot = na4 + nb4 + nc4;
    for (size_t i = (size_t)blockIdx.x*256 + threadIdx.x; i < tot;
         i += (size_t)gridDim.x*256) {
        const float* s; _Float16* d; size_t off;
        if (i < na4)            { s = a;    d = da; off = i; }
        else if (i < na4 + nb4) { s = bsrc; d = db; off = i - na4; }
        else                    { s = c;    d = dc; off = i - na4 - nb4; }
        float4 v = ((const float4*)s)[off];
        union { _Float16 h[4]; uint2 u; } o;
        o.h[0] = (_Float16)v.x; o.h[1] = (_Float16)v.y;
        o.h[2] = (_Float16)v.z; o.h[3] = (_Float16)v.w;
        ((uint2*)d)[off] = o.u;
    }
}

// ---------------------------------------------------------------------------
// QKV MFMA GEMM: 128x128 tile, BK=32, 4 waves; fp16 scatter into q/k/v
// ---------------------------------------------------------------------------
__global__ __launch_bounds__(256) void qkv_mfma(
    const _Float16* __restrict__ A, const _Float16* __restrict__ Wt,
    const float* __restrict__ bias,
    _Float16* __restrict__ qd, _Float16* __restrict__ kd, _Float16* __restrict__ vd)
{
    __shared__ _Float16 As[128*LST];
    __shared__ _Float16 Bs[128*LST];

    const int tid = threadIdx.x;
    const int wid = tid >> 6, lane = tid & 63;
    const int l15 = lane & 15, g = lane >> 4;
    const int wr = wid >> 1, wc = wid & 1;
    const int m0 = blockIdx.x * 128;
    const int n0 = blockIdx.y * 128;
    const int r = tid >> 2, c = tid & 3;

    f32x4 acc[4][4] = {};
    for (int k0 = 0; k0 < 512; k0 += 32) {
        f16x8 av0 = *(const f16x8*)(A  + (size_t)(m0 + r)*512      + k0 + c*8);
        f16x8 av1 = *(const f16x8*)(A  + (size_t)(m0 + r + 64)*512 + k0 + c*8);
        f16x8 bv0 = *(const f16x8*)(Wt + (size_t)(n0 + r)*512      + k0 + c*8);
        f16x8 bv1 = *(const f16x8*)(Wt + (size_t)(n0 + r + 64)*512 + k0 + c*8);
        __syncthreads();
        *(f16x8*)(&As[r*LST + c*8])        = av0;
        *(f16x8*)(&As[(r + 64)*LST + c*8]) = av1;
        *(f16x8*)(&Bs[r*LST + c*8])        = bv0;
        *(f16x8*)(&Bs[(r + 64)*LST + c*8]) = bv1;
        __syncthreads();
        f16x8 af[4], bf[4];
        #pragma unroll
        for (int f = 0; f < 4; ++f) {
            af[f] = *(const f16x8*)(&As[(wr*64 + f*16 + l15)*LST + g*8]);
            bf[f] = *(const f16x8*)(&Bs[(wc*64 + f*16 + l15)*LST + g*8]);
        }
        #pragma unroll
        for (int fi = 0; fi < 4; ++fi)
            #pragma unroll
            for (int fj = 0; fj < 4; ++fj)
                acc[fi][fj] = __builtin_amdgcn_mfma_f32_16x16x32_f16(
                    af[fi], bf[fj], acc[fi][fj], 0, 0, 0);
    }

    const int which = n0 >> 9;
    _Float16* dst = (which == 0) ? qd : (which == 1) ? kd : vd;
    #pragma unroll
    for (int fj = 0; fj < 4; ++fj) {
        const int col = n0 + wc*64 + fj*16 + l15;
        const int h = (col >> 6) & 7;
        const float bc = bias[col];
        #pragma unroll
        for (int fi = 0; fi < 4; ++fi)
            #pragma unroll
            for (int rr = 0; rr < 4; ++rr) {
                int grow = m0 + wr*64 + fi*16 + g*4 + rr;
                int b = grow >> 11, s = grow & 2047;
                dst[(((size_t)(b*HH + h))*SS + s)*DH + (col & 63)] =
                    (_Float16)(acc[fi][fj][rr] + bc);
            }
    }
}

// ---------------------------------------------------------------------------
// Out-proj MFMA GEMM + fused per-column max over the 128-row tile
// ---------------------------------------------------------------------------
__global__ __launch_bounds__(256) void out_mfma(
    const _Float16* __restrict__ A, const _Float16* __restrict__ Wt,
    const float* __restrict__ bias, float* __restrict__ part)
{
    __shared__ _Float16 As[128*LST];
    __shared__ _Float16 Bs[128*LST];

    const int tid = threadIdx.x;
    const int wid = tid >> 6, lane = tid & 63;
    const int l15 = lane & 15, g = lane >> 4;
    const int wr = wid >> 1, wc = wid & 1;
    const int m0 = blockIdx.x * 128;
    const int n0 = blockIdx.y * 128;
    const int r = tid >> 2, c = tid & 3;

    f32x4 acc[4][4] = {};
    for (int k0 = 0; k0 < 512; k0 += 32) {
        f16x8 av0 = *(const f16x8*)(A  + (size_t)(m0 + r)*512      + k0 + c*8);
        f16x8 av1 = *(const f16x8*)(A  + (size_t)(m0 + r + 64)*512 + k0 + c*8);
        f16x8 bv0 = *(const f16x8*)(Wt + (size_t)(n0 + r)*512      + k0 + c*8);
        f16x8 bv1 = *(const f16x8*)(Wt + (size_t)(n0 + r + 64)*512 + k0 + c*8);
        __syncthreads();
        *(f16x8*)(&As[r*LST + c*8])        = av0;
        *(f16x8*)(&As[(r + 64)*LST + c*8]) = av1;
        *(f16x8*)(&Bs[r*LST + c*8])        = bv0;
        *(f16x8*)(&Bs[(r + 64)*LST + c*8]) = bv1;
        __syncthreads();
        f16x8 af[4], bf[4];
        #pragma unroll
        for (int f = 0; f < 4; ++f) {
            af[f] = *(const f16x8*)(&As[(wr*64 + f*16 + l15)*LST + g*8]);
            bf[f] = *(const f16x8*)(&Bs[(wc*64 + f*16 + l15)*LST + g*8]);
        }
        #pragma unroll
        for (int fi = 0; fi < 4; ++fi)
            #pragma unroll
            for (int fj = 0; fj < 4; ++fj)
                acc[fi][fj] = __builtin_amdgcn_mfma_f32_16x16x32_f16(
                    af[fi], bf[fj], acc[fi][fj], 0, 0, 0);
    }

    __syncthreads();
    float* red = (float*)As;               // [2][128]
    #pragma unroll
    for (int fj = 0; fj < 4; ++fj) {
        float cm = -1e30f;
        #pragma unroll
        for (int fi = 0; fi < 4; ++fi)
            #pragma unroll
            for (int rr = 0; rr < 4; ++rr)
                cm = fmaxf(cm, acc[fi][fj][rr]);
        cm = fmaxf(cm, __shfl_xor(cm, 16));
        cm = fmaxf(cm, __shfl_xor(cm, 32));
        if (g == 0) red[wr*128 + wc*64 + fj*16 + l15] = cm;
    }
    __syncthreads();
    if (tid < 128) {
        float m = fmaxf(red[tid], red[128 + tid]) + bias[n0 + tid];
        part[(size_t)blockIdx.x * EE + n0 + tid] = m;
    }
}

// ---------------------------------------------------------------------------
// MFMA banded attention. vt staged with XOR block-swizzle; softmax covers all
// 288 columns: 16 thr/row x 18 elems (2x b128 + 1x f16x2).
// ---------------------------------------------------------------------------
__global__ __launch_bounds__(512, 4) void attn_mfma(
    const _Float16* __restrict__ qd, const _Float16* __restrict__ kd,
    const _Float16* __restrict__ vd, _Float16* __restrict__ ctx,
    float2* __restrict__ stats)
{
    __shared__ _Float16 sc[32 * SWH];   // 18944 B
    __shared__ _Float16 vt[64 * VTP];   // 37888 B

    const int tid  = threadIdx.x;
    const int wid  = tid >> 6;
    const int lane = tid & 63;
    const int l15  = lane & 15;
    const int g    = lane >> 4;
    const int ti = blockIdx.x;
    const int b  = blockIdx.y;
    const int h  = blockIdx.z;
    const int i0 = ti * 32;
    const int jlo = (i0 - WW > 0) ? i0 - WW : 0;
    const int jhi = (i0 + 31 + WW < SS - 1) ? i0 + 31 + WW : SS - 1;
    const int nj = jhi - jlo + 1;        // multiple of 32, <= 288
    const int NC = nj >> 4;

    const _Float16* qb = qd + ((size_t)(b*HH + h))*SS*DH;
    const _Float16* kb = kd + ((size_t)(b*HH + h))*SS*DH;
    const _Float16* vb = vd + ((size_t)(b*HH + h))*SS*DH;

    // ---- stage V^T with XOR block-swizzle: col' = (blk ^ (d>>3))*8 + off ----
    for (int idx = tid; idx < 288*8; idx += 512) {
        int row = idx >> 3, dg = idx & 7;       // dg = d0>>3
        int d0 = dg * 8;
        int j = jlo + row;
        f16x8 vv = {};
        if (j <= jhi) vv = *(const f16x8*)(vb + (size_t)j*DH + d0);
        int blk = row >> 3, off = row & 7;
        int xb = (blk < 32) ? (blk ^ dg) : blk;
        _Float16* col = &vt[(size_t)d0*VTP + xb*8 + off];
        #pragma unroll
        for (int e = 0; e < 8; ++e)
            col[e*VTP] = vv[e];
    }

    // ---- pad fill for edge tiles: sc[:, nj:288) = -60000 ----
    if (nj < 288) {
        int row = tid >> 4, pt = tid & 15;
        for (int jj = nj + pt; jj < 288; jj += 16)
            sc[row*SWH + jj] = (_Float16)(-60000.f);
    }

    // ---- QK^T via MFMA ----
    {
        const int rh = wid & 1, cgrp = wid >> 1;
        const int qrow = i0 + rh*16 + l15;
        f16x8 aq0 = *(const f16x8*)(qb + (size_t)qrow*DH +      g*8);
        f16x8 aq1 = *(const f16x8*)(qb + (size_t)qrow*DH + 32 + g*8);
        #pragma unroll
        for (int t = 0; t < 5; ++t) {
            int c = cgrp + t*4;
            if (c < NC) {
                int jj = c*16 + l15;
                int j  = jlo + jj;
                f16x8 bk0 = *(const f16x8*)(kb + (size_t)j*DH +      g*8);
                f16x8 bk1 = *(const f16x8*)(kb + (size_t)j*DH + 32 + g*8);
                f32x4 s = {0.f, 0.f, 0.f, 0.f};
                s = __builtin_amdgcn_mfma_f32_16x16x32_f16(aq0, bk0, s, 0, 0, 0);
                s = __builtin_amdgcn_mfma_f32_16x16x32_f16(aq1, bk1, s, 0, 0, 0);
                #pragma unroll
                for (int r = 0; r < 4; ++r) {
                    int srow = rh*16 + g*4 + r;
                    int i = i0 + srow;
                    int dd = i - j; if (dd < 0) dd = -dd;
                    float val = (dd <= WW) ? s[r]*0.125f : -60000.f;
                    sc[srow*SWH + jj] = (_Float16)val;
                }
            }
        }
    }
    __syncthreads();

    // ---- exact softmax: 16 thr/row x 18 elems (covers all 288 cols) ----
    {
        const int qi = tid >> 4, pt = tid & 15;
        _Float16* srow = &sc[qi*SWH];
        f16x8 v0 = *(const f16x8*)&srow[pt*16];
        f16x8 v1 = *(const f16x8*)&srow[pt*16 + 8];
        f16x2 v2 = *(const f16x2*)&srow[256 + pt*2];
        float x[18];
        #pragma unroll
        for (int e = 0; e < 8; ++e) { x[e] = (float)v0[e]; x[8+e] = (float)v1[e]; }
        x[16] = (float)v2[0]; x[17] = (float)v2[1];

        float mrow = x[0];
        #pragma unroll
        for (int e = 1; e < 18; ++e) mrow = fmaxf(mrow, x[e]);
        #pragma unroll
        for (int o = 1; o < 16; o <<= 1) mrow = fmaxf(mrow, __shfl_xor(mrow, o));

        float ssum = 0.f;
        #pragma unroll
        for (int e = 0; e < 18; ++e) { x[e] = __expf(x[e] - mrow); ssum += x[e]; }
        #pragma unroll
        for (int o = 1; o < 16; o <<= 1) ssum += __shfl_xor(ssum, o);
        const float inv = 1.0f / ssum;

        f16x8 p0, p1;
        f16x2 p2;
        #pragma unroll
        for (int e = 0; e < 8; ++e) {
            p0[e] = (_Float16)(x[e]   * inv);
            p1[e] = (_Float16)(x[8+e] * inv);
        }
        p2[0] = (_Float16)(x[16] * inv);
        p2[1] = (_Float16)(x[17] * inv);
        *(f16x8*)&srow[pt*16]     = p0;
        *(f16x8*)&srow[pt*16 + 8] = p1;
        *(f16x2*)&srow[256 + pt*2] = p2;
        if (pt == 0)
            stats[((size_t)(b*HH + h))*SS + i0 + qi] = make_float2(mrow, inv);
    }
    __syncthreads();

    // ---- PV via MFMA: wave -> (rowhalf, d-tile); swizzled vt reads ----
    {
        const int rh = wid & 1, dt = wid >> 1;
        const int d = dt*16 + l15;
        const int dg = d >> 3;
        f32x4 acc = {0.f, 0.f, 0.f, 0.f};
        #pragma unroll
        for (int ks = 0; ks < 9; ++ks) {
            int blk = ks*4 + g;
            int xb = (blk < 32) ? (blk ^ dg) : blk;
            f16x8 ap = *(const f16x8*)&sc[(rh*16 + l15)*SWH + ks*32 + g*8];
            f16x8 bv = *(const f16x8*)&vt[(size_t)d*VTP + xb*8];
            acc = __builtin_amdgcn_mfma_f32_16x16x32_f16(ap, bv, acc, 0, 0, 0);
        }
        #pragma unroll
        for (int r = 0; r < 4; ++r) {
            int row = i0 + rh*16 + g*4 + r;
            ctx[((size_t)(b*SS + row))*EE + h*DH + dt*16 + l15] = (_Float16)acc[r];
        }
    }
}

// ---------------------------------------------------------------------------
// Weights: block=(ti,b,z), z = column-third of the 288-window. Recompute
// QK^T per head via MFMA, p from stats, head-mean -> write disjoint slice
// of the full 2048-wide rows (zeros included).
// ---------------------------------------------------------------------------
__global__ __launch_bounds__(256) void weights_k(
    const _Float16* __restrict__ qd, const _Float16* __restrict__ kd,
    const float2* __restrict__ stats, float* __restrict__ wout)
{
    __shared__ float wacc[32 * WST];    // 12416 B

    const int tid  = threadIdx.x;
    const int wid  = tid >> 6;          // 0..3
    const int lane = tid & 63;
    const int l15  = lane & 15;
    const int g    = lane >> 4;
    const int ti = blockIdx.x;
    const int b  = blockIdx.y;
    const int z  = blockIdx.z;          // 0..2
    const int i0 = ti * 32;
    const int jlo = (i0 - WW > 0) ? i0 - WW : 0;
    const int jhi = (i0 + 31 + WW < SS - 1) ? i0 + 31 + WW : SS - 1;
    const int nj = jhi - jlo + 1;
    const int NC = nj >> 4;

    const int rh = wid & 1, cg2 = wid >> 1;   // 2 rowhalves x 2 colgroups
    const int qrow = i0 + rh*16 + l15;

    float ws[3][4];
    #pragma unroll
    for (int t = 0; t < 3; ++t)
        #pragma unroll
        for (int r = 0; r < 4; ++r) ws[t][r] = 0.f;

    for (int h = 0; h < HH; ++h) {
        const _Float16* qb = qd + ((size_t)(b*HH + h))*SS*DH;
        const _Float16* kb = kd + ((size_t)(b*HH + h))*SS*DH;
        f16x8 aq0 = *(const f16x8*)(qb + (size_t)qrow*DH +      g*8);
        f16x8 aq1 = *(const f16x8*)(qb + (size_t)qrow*DH + 32 + g*8);
        float2 st[4];
        #pragma unroll
        for (int r = 0; r < 4; ++r)
            st[r] = stats[((size_t)(b*HH + h))*SS + i0 + rh*16 + g*4 + r];

        #pragma unroll
        for (int t = 0; t < 3; ++t) {
            int lt = cg2 + t*2;                 // 0..5
            int c = z*6 + lt;
            if (c < NC) {
                int jj = c*16 + l15;
                int j  = jlo + jj;
                f16x8 bk0 = *(const f16x8*)(kb + (size_t)j*DH +      g*8);
                f16x8 bk1 = *(const f16x8*)(kb + (size_t)j*DH + 32 + g*8);
                f32x4 s = {0.f, 0.f, 0.f, 0.f};
                s = __builtin_amdgcn_mfma_f32_16x16x32_f16(aq0, bk0, s, 0, 0, 0);
                s = __builtin_amdgcn_mfma_f32_16x16x32_f16(aq1, bk1, s, 0, 0, 0);
                #pragma unroll
                for (int r = 0; r < 4; ++r) {
                    int i = i0 + rh*16 + g*4 + r;
                    int dd = i - j; if (dd < 0) dd = -dd;
                    if (dd <= WW)
                        ws[t][r] += __expf(s[r]*0.125f - st[r].x) * st[r].y;
                }
            }
        }
    }

    #pragma unroll
    for (int t = 0; t < 3; ++t) {
        int lt = cg2 + t*2, c = z*6 + lt;
        if (c < NC) {
            #pragma unroll
            for (int r = 0; r < 4; ++r)
                wacc[(rh*16 + g*4 + r)*WST + lt*16 + l15] = ws[t][r];
        }
    }
    __syncthreads();

    // write phase: block owns absolute cols [lo, hi), partitioned by z
    int lo, hi;
    if (z == 0)      { lo = 0;        hi = jlo + 96; }
    else if (z == 1) { lo = jlo + 96; hi = (jlo + 192 < SS) ? jlo + 192 : SS; }
    else             { lo = (jlo + 192 < SS) ? jlo + 192 : SS; hi = SS; }

    const int row = tid >> 3;          // 32 rows, 8 threads each
    const int pt  = tid & 7;
    const int i = i0 + row;
    const int blo = (i - WW > 0) ? i - WW : 0;
    const int bhi = (i + WW < SS - 1) ? i + WW : SS - 1;
    const int cbase = jlo + z*96;
    float* wrow = wout + ((size_t)(b*SS + i))*SS;
    for (int j4 = lo + pt*4; j4 < hi; j4 += 32) {
        float4 o;
        float* oo = (float*)&o;
        #pragma unroll
        for (int e = 0; e < 4; ++e) {
            int j = j4 + e;
            oo[e] = (j >= blo && j <= bhi)
                  ? wacc[row*WST + (j - cbase)] * 0.125f : 0.f;
        }
        *(float4*)(wrow + j4) = o;
    }
}

__global__ void pool_final(const float* __restrict__ part, float* __restrict__ pooled)
{
    int e = blockIdx.x * 256 + threadIdx.x;   // grid.x = 2
    int b = blockIdx.y;
    float m = -1e30f;
    #pragma unroll
    for (int t = 0; t < 16; ++t)
        m = fmaxf(m, part[((size_t)(b*16 + t))*EE + e]);
    pooled[b*EE + e] = m;
}

// ---------------------------------------------------------------------------
extern "C" void kernel_launch(void* const* d_in, const int* in_sizes, int n_in,
                              void* d_out, int out_size, void* d_ws, size_t ws_size,
                              hipStream_t stream)
{
    const float* emb = (const float*)d_in[0];
    const float* ipw = (const float*)d_in[1];
    const float* ipb = (const float*)d_in[2];
    const float* ow  = (const float*)d_in[3];
    const float* ob  = (const float*)d_in[4];

    float* pooled = (float*)d_out;                       // [4,512]
    float* wout   = pooled + (size_t)BB*EE;              // [4,2048,2048]

    const size_t headsz = (size_t)BB*HH*SS*DH;
    _Float16* q    = (_Float16*)d_ws;
    _Float16* k    = q + headsz;
    _Float16* v    = k + headsz;
    _Float16* ctx  = v + headsz;                         // [8192,512] fp16
    _Float16* A16  = ctx + (size_t)MM*EE;                // emb fp16
    _Float16* W16  = A16 + (size_t)MM*EE;                // in_proj_w fp16
    _Float16* OW16 = W16 + (size_t)3*EE*EE;              // out_w fp16
    float* part    = (float*)(OW16 + (size_t)EE*EE);     // [64,512]
    float2* stats  = (float2*)(part + 64*EE);            // [4,8,2048]

    convert3<<<1280, 256, 0, stream>>>(emb, ipw, ow, A16, W16, OW16);
    qkv_mfma<<<dim3(64, 12), 256, 0, stream>>>(A16, W16, ipb, q, k, v);
    attn_mfma<<<dim3(NTILE, BB, HH), 512, 0, stream>>>(q, k, v, ctx, stats);
    weights_k<<<dim3(NTILE, BB, 3), 256, 0, stream>>>(q, k, stats, wout);
    out_mfma<<<dim3(64, 4), 256, 0, stream>>>(ctx, OW16, ob, part);
    pool_final<<<dim3(2, BB), 256, 0, stream>>>(part, pooled);
}

// Round 7
// 117.634 us; speedup vs baseline: 6.4787x; 1.0654x over previous
//
#include <hip/hip_runtime.h>
#include <math.h>

#define BB   4
#define SS   2048
#define EE   512
#define HH   8
#define DH   64
#define WW   128
#define MM   (BB*SS)      // 8192
#define NTILE (SS/32)     // 64 q-tiles per batch
#define SWH  296          // fp16 score stride
#define VTP  296          // fp16 V^T stride (swizzled cols stay < 288)
#define WST  97           // weights-kernel fp32 LDS stride
#define BK   64           // GEMM K-step (halves)

typedef _Float16 f16x8 __attribute__((ext_vector_type(8)));
typedef _Float16 f16x2 __attribute__((ext_vector_type(2)));
typedef float    f32x4 __attribute__((ext_vector_type(4)));

// async global->LDS, 16B per lane; LDS dest = uniform base + lane*16
#define GLOAD16(gp, lp) __builtin_amdgcn_global_load_lds( \
    (const __attribute__((address_space(1))) void*)(gp),  \
    (__attribute__((address_space(3))) void*)(lp), 16, 0, 0)

// ---------------------------------------------------------------------------
// fp32 -> fp16 conversion for emb / in_proj_w / out_w
// ---------------------------------------------------------------------------
__global__ __launch_bounds__(256) void convert3(
    const float* __restrict__ a, const float* __restrict__ bsrc,
    const float* __restrict__ c,
    _Float16* __restrict__ da, _Float16* __restrict__ db, _Float16* __restrict__ dc)
{
    const size_t na4 = (size_t)MM*EE/4;
    const size_t nb4 = (size_t)3*EE*EE/4;
    const size_t nc4 = (size_t)EE*EE/4;
    const size_t tot = na4 + nb4 + nc4;
    for (size_t i = (size_t)blockIdx.x*256 + threadIdx.x; i < tot;
         i += (size_t)gridDim.x*256) {
        const float* s; _Float16* d; size_t off;
        if (i < na4)            { s = a;    d = da; off = i; }
        else if (i < na4 + nb4) { s = bsrc; d = db; off = i - na4; }
        else                    { s = c;    d = dc; off = i - na4 - nb4; }
        float4 v = ((const float4*)s)[off];
        union { _Float16 h[4]; uint2 u; } o;
        o.h[0] = (_Float16)v.x; o.h[1] = (_Float16)v.y;
        o.h[2] = (_Float16)v.z; o.h[3] = (_Float16)v.w;
        ((uint2*)d)[off] = o.u;
    }
}

// ---------------------------------------------------------------------------
// QKV MFMA GEMM, 128x128 tile, BK=64, global_load_lds staging with XOR
// chunk-swizzle (source pre-swizzled, linear LDS dest, swizzled ds_read).
// ---------------------------------------------------------------------------
__global__ __launch_bounds__(256) void qkv_mfma(
    const _Float16* __restrict__ A, const _Float16* __restrict__ Wt,
    const float* __restrict__ bias,
    _Float16* __restrict__ qd, _Float16* __restrict__ kd, _Float16* __restrict__ vd)
{
    __shared__ _Float16 As[128*BK];   // 16 KB
    __shared__ _Float16 Bs[128*BK];   // 16 KB

    const int tid = threadIdx.x;
    const int wid = tid >> 6, lane = tid & 63;
    const int l15 = lane & 15, g = lane >> 4;
    const int wr = wid >> 1, wc = wid & 1;
    const int m0 = blockIdx.x * 128;
    const int n0 = blockIdx.y * 128;

    // staging: instr t covers rows wid*32+t*8 .. +7; lane -> (row, chunk)
    const int lrow = lane >> 3;               // 0..7 within 8-row group
    const int swz  = (lane & 7) ^ lrow;       // pre-swizzled 16B chunk
    const _Float16* Ab = A  + (size_t)(m0 + wid*32 + lrow)*512 + swz*8;
    const _Float16* Bb = Wt + (size_t)(n0 + wid*32 + lrow)*512 + swz*8;

    f32x4 acc[4][4] = {};
    for (int k0 = 0; k0 < 512; k0 += BK) {
        __syncthreads();                       // prior tile's reads done
        #pragma unroll
        for (int t = 0; t < 4; ++t) {
            GLOAD16(Ab + (size_t)t*8*512 + k0, &As[(wid*32 + t*8)*BK]);
            GLOAD16(Bb + (size_t)t*8*512 + k0, &Bs[(wid*32 + t*8)*BK]);
        }
        __syncthreads();                       // staged data visible

        f16x8 af[2][4], bf[2][4];
        #pragma unroll
        for (int ks = 0; ks < 2; ++ks)
            #pragma unroll
            for (int f = 0; f < 4; ++f) {
                const int ch = ((ks*4 + g) ^ (l15 & 7)) * 8;
                af[ks][f] = *(const f16x8*)&As[(wr*64 + f*16 + l15)*BK + ch];
                bf[ks][f] = *(const f16x8*)&Bs[(wc*64 + f*16 + l15)*BK + ch];
            }
        #pragma unroll
        for (int ks = 0; ks < 2; ++ks)
            #pragma unroll
            for (int fi = 0; fi < 4; ++fi)
                #pragma unroll
                for (int fj = 0; fj < 4; ++fj)
                    acc[fi][fj] = __builtin_amdgcn_mfma_f32_16x16x32_f16(
                        af[ks][fi], bf[ks][fj], acc[fi][fj], 0, 0, 0);
    }

    const int which = n0 >> 9;
    _Float16* dst = (which == 0) ? qd : (which == 1) ? kd : vd;
    #pragma unroll
    for (int fj = 0; fj < 4; ++fj) {
        const int col = n0 + wc*64 + fj*16 + l15;
        const int h = (col >> 6) & 7;
        const float bc = bias[col];
        #pragma unroll
        for (int fi = 0; fi < 4; ++fi)
            #pragma unroll
            for (int rr = 0; rr < 4; ++rr) {
                int grow = m0 + wr*64 + fi*16 + g*4 + rr;
                int b = grow >> 11, s = grow & 2047;
                dst[(((size_t)(b*HH + h))*SS + s)*DH + (col & 63)] =
                    (_Float16)(acc[fi][fj][rr] + bc);
            }
    }
}

// ---------------------------------------------------------------------------
// Out-proj MFMA GEMM (same staging) + fused per-column max over 128-row tile
// ---------------------------------------------------------------------------
__global__ __launch_bounds__(256) void out_mfma(
    const _Float16* __restrict__ A, const _Float16* __restrict__ Wt,
    const float* __restrict__ bias, float* __restrict__ part)
{
    __shared__ _Float16 As[128*BK];
    __shared__ _Float16 Bs[128*BK];

    const int tid = threadIdx.x;
    const int wid = tid >> 6, lane = tid & 63;
    const int l15 = lane & 15, g = lane >> 4;
    const int wr = wid >> 1, wc = wid & 1;
    const int m0 = blockIdx.x * 128;
    const int n0 = blockIdx.y * 128;

    const int lrow = lane >> 3;
    const int swz  = (lane & 7) ^ lrow;
    const _Float16* Ab = A  + (size_t)(m0 + wid*32 + lrow)*512 + swz*8;
    const _Float16* Bb = Wt + (size_t)(n0 + wid*32 + lrow)*512 + swz*8;

    f32x4 acc[4][4] = {};
    for (int k0 = 0; k0 < 512; k0 += BK) {
        __syncthreads();
        #pragma unroll
        for (int t = 0; t < 4; ++t) {
            GLOAD16(Ab + (size_t)t*8*512 + k0, &As[(wid*32 + t*8)*BK]);
            GLOAD16(Bb + (size_t)t*8*512 + k0, &Bs[(wid*32 + t*8)*BK]);
        }
        __syncthreads();

        f16x8 af[2][4], bf[2][4];
        #pragma unroll
        for (int ks = 0; ks < 2; ++ks)
            #pragma unroll
            for (int f = 0; f < 4; ++f) {
                const int ch = ((ks*4 + g) ^ (l15 & 7)) * 8;
                af[ks][f] = *(const f16x8*)&As[(wr*64 + f*16 + l15)*BK + ch];
                bf[ks][f] = *(const f16x8*)&Bs[(wc*64 + f*16 + l15)*BK + ch];
            }
        #pragma unroll
        for (int ks = 0; ks < 2; ++ks)
            #pragma unroll
            for (int fi = 0; fi < 4; ++fi)
                #pragma unroll
                for (int fj = 0; fj < 4; ++fj)
                    acc[fi][fj] = __builtin_amdgcn_mfma_f32_16x16x32_f16(
                        af[ks][fi], bf[ks][fj], acc[fi][fj], 0, 0, 0);
    }

    __syncthreads();
    float* red = (float*)As;               // [2][128]
    #pragma unroll
    for (int fj = 0; fj < 4; ++fj) {
        float cm = -1e30f;
        #pragma unroll
        for (int fi = 0; fi < 4; ++fi)
            #pragma unroll
            for (int rr = 0; rr < 4; ++rr)
                cm = fmaxf(cm, acc[fi][fj][rr]);
        cm = fmaxf(cm, __shfl_xor(cm, 16));
        cm = fmaxf(cm, __shfl_xor(cm, 32));
        if (g == 0) red[wr*128 + wc*64 + fj*16 + l15] = cm;
    }
    __syncthreads();
    if (tid < 128) {
        float m = fmaxf(red[tid], red[128 + tid]) + bias[n0 + tid];
        part[(size_t)blockIdx.x * EE + n0 + tid] = m;
    }
}

// ---------------------------------------------------------------------------
// MFMA banded attention, XCD-aware block swizzle (2048 = 8 x 256 bijective):
// each XCD owns a contiguous run of q-tiles for fixed (b,h) -> K/V L2-hit.
// ---------------------------------------------------------------------------
__global__ __launch_bounds__(512, 4) void attn_mfma(
    const _Float16* __restrict__ qd, const _Float16* __restrict__ kd,
    const _Float16* __restrict__ vd, _Float16* __restrict__ ctx,
    float2* __restrict__ stats)
{
    __shared__ _Float16 sc[32 * SWH];   // 18944 B
    __shared__ _Float16 vt[64 * VTP];   // 37888 B

    const int tid  = threadIdx.x;
    const int wid  = tid >> 6;
    const int lane = tid & 63;
    const int l15  = lane & 15;
    const int g    = lane >> 4;

    const int lin = blockIdx.x + (blockIdx.y << 6) + (blockIdx.z << 8); // 0..2047
    const int nid = (lin & 7) * 256 + (lin >> 3);                       // bijective
    const int ti = nid & 63;
    const int b  = (nid >> 6) & 3;
    const int h  = nid >> 8;

    const int i0 = ti * 32;
    const int jlo = (i0 - WW > 0) ? i0 - WW : 0;
    const int jhi = (i0 + 31 + WW < SS - 1) ? i0 + 31 + WW : SS - 1;
    const int nj = jhi - jlo + 1;        // multiple of 32, <= 288
    const int NC = nj >> 4;

    const _Float16* qb = qd + ((size_t)(b*HH + h))*SS*DH;
    const _Float16* kb = kd + ((size_t)(b*HH + h))*SS*DH;
    const _Float16* vb = vd + ((size_t)(b*HH + h))*SS*DH;

    // ---- stage V^T with XOR block-swizzle: col' = (blk ^ (d>>3))*8 + off ----
    for (int idx = tid; idx < 288*8; idx += 512) {
        int row = idx >> 3, dg = idx & 7;
        int d0 = dg * 8;
        int j = jlo + row;
        f16x8 vv = {};
        if (j <= jhi) vv = *(const f16x8*)(vb + (size_t)j*DH + d0);
        int blk = row >> 3, off = row & 7;
        int xb = (blk < 32) ? (blk ^ dg) : blk;
        _Float16* col = &vt[(size_t)d0*VTP + xb*8 + off];
        #pragma unroll
        for (int e = 0; e < 8; ++e)
            col[e*VTP] = vv[e];
    }

    if (nj < 288) {
        int row = tid >> 4, pt = tid & 15;
        for (int jj = nj + pt; jj < 288; jj += 16)
            sc[row*SWH + jj] = (_Float16)(-60000.f);
    }

    // ---- QK^T via MFMA ----
    {
        const int rh = wid & 1, cgrp = wid >> 1;
        const int qrow = i0 + rh*16 + l15;
        f16x8 aq0 = *(const f16x8*)(qb + (size_t)qrow*DH +      g*8);
        f16x8 aq1 = *(const f16x8*)(qb + (size_t)qrow*DH + 32 + g*8);
        #pragma unroll
        for (int t = 0; t < 5; ++t) {
            int c = cgrp + t*4;
            if (c < NC) {
                int jj = c*16 + l15;
                int j  = jlo + jj;
                f16x8 bk0 = *(const f16x8*)(kb + (size_t)j*DH +      g*8);
                f16x8 bk1 = *(const f16x8*)(kb + (size_t)j*DH + 32 + g*8);
                f32x4 s = {0.f, 0.f, 0.f, 0.f};
                s = __builtin_amdgcn_mfma_f32_16x16x32_f16(aq0, bk0, s, 0, 0, 0);
                s = __builtin_amdgcn_mfma_f32_16x16x32_f16(aq1, bk1, s, 0, 0, 0);
                #pragma unroll
                for (int r = 0; r < 4; ++r) {
                    int srow = rh*16 + g*4 + r;
                    int i = i0 + srow;
                    int dd = i - j; if (dd < 0) dd = -dd;
                    float val = (dd <= WW) ? s[r]*0.125f : -60000.f;
                    sc[srow*SWH + jj] = (_Float16)val;
                }
            }
        }
    }
    __syncthreads();

    // ---- exact softmax: 16 thr/row x 18 elems (covers all 288 cols) ----
    {
        const int qi = tid >> 4, pt = tid & 15;
        _Float16* srow = &sc[qi*SWH];
        f16x8 v0 = *(const f16x8*)&srow[pt*16];
        f16x8 v1 = *(const f16x8*)&srow[pt*16 + 8];
        f16x2 v2 = *(const f16x2*)&srow[256 + pt*2];
        float x[18];
        #pragma unroll
        for (int e = 0; e < 8; ++e) { x[e] = (float)v0[e]; x[8+e] = (float)v1[e]; }
        x[16] = (float)v2[0]; x[17] = (float)v2[1];

        float mrow = x[0];
        #pragma unroll
        for (int e = 1; e < 18; ++e) mrow = fmaxf(mrow, x[e]);
        #pragma unroll
        for (int o = 1; o < 16; o <<= 1) mrow = fmaxf(mrow, __shfl_xor(mrow, o));

        float ssum = 0.f;
        #pragma unroll
        for (int e = 0; e < 18; ++e) { x[e] = __expf(x[e] - mrow); ssum += x[e]; }
        #pragma unroll
        for (int o = 1; o < 16; o <<= 1) ssum += __shfl_xor(ssum, o);
        const float inv = 1.0f / ssum;

        f16x8 p0, p1;
        f16x2 p2;
        #pragma unroll
        for (int e = 0; e < 8; ++e) {
            p0[e] = (_Float16)(x[e]   * inv);
            p1[e] = (_Float16)(x[8+e] * inv);
        }
        p2[0] = (_Float16)(x[16] * inv);
        p2[1] = (_Float16)(x[17] * inv);
        *(f16x8*)&srow[pt*16]      = p0;
        *(f16x8*)&srow[pt*16 + 8]  = p1;
        *(f16x2*)&srow[256 + pt*2] = p2;
        if (pt == 0)
            stats[((size_t)(b*HH + h))*SS + i0 + qi] = make_float2(mrow, inv);
    }
    __syncthreads();

    // ---- PV via MFMA: wave -> (rowhalf, d-tile); swizzled vt reads ----
    {
        const int rh = wid & 1, dt = wid >> 1;
        const int d = dt*16 + l15;
        const int dg = d >> 3;
        f32x4 acc = {0.f, 0.f, 0.f, 0.f};
        #pragma unroll
        for (int ks = 0; ks < 9; ++ks) {
            int blk = ks*4 + g;
            int xb = (blk < 32) ? (blk ^ dg) : blk;
            f16x8 ap = *(const f16x8*)&sc[(rh*16 + l15)*SWH + ks*32 + g*8];
            f16x8 bv = *(const f16x8*)&vt[(size_t)d*VTP + xb*8];
            acc = __builtin_amdgcn_mfma_f32_16x16x32_f16(ap, bv, acc, 0, 0, 0);
        }
        #pragma unroll
        for (int r = 0; r < 4; ++r) {
            int row = i0 + rh*16 + g*4 + r;
            ctx[((size_t)(b*SS + row))*EE + h*DH + dt*16 + l15] = (_Float16)acc[r];
        }
    }
}

// ---------------------------------------------------------------------------
// Weights: block=(ti,b,z) XCD-swizzled (768 = 8 x 96). Recompute QK^T per
// head via MFMA, p from stats, head-mean -> disjoint slice of full rows.
// ---------------------------------------------------------------------------
__global__ __launch_bounds__(256) void weights_k(
    const _Float16* __restrict__ qd, const _Float16* __restrict__ kd,
    const float2* __restrict__ stats, float* __restrict__ wout)
{
    __shared__ float wacc[32 * WST];    // 12416 B

    const int tid  = threadIdx.x;
    const int wid  = tid >> 6;
    const int lane = tid & 63;
    const int l15  = lane & 15;
    const int g    = lane >> 4;

    const int lin = blockIdx.x + (blockIdx.y << 6) + (blockIdx.z << 8); // 0..767
    const int nid = (lin & 7) * 96 + (lin >> 3);                        // bijective
    const int ti = nid & 63;
    const int b  = (nid >> 6) & 3;
    const int z  = nid >> 8;

    const int i0 = ti * 32;
    const int jlo = (i0 - WW > 0) ? i0 - WW : 0;
    const int jhi = (i0 + 31 + WW < SS - 1) ? i0 + 31 + WW : SS - 1;
    const int nj = jhi - jlo + 1;
    const int NC = nj >> 4;

    const int rh = wid & 1, cg2 = wid >> 1;
    const int qrow = i0 + rh*16 + l15;

    float ws[3][4];
    #pragma unroll
    for (int t = 0; t < 3; ++t)
        #pragma unroll
        for (int r = 0; r < 4; ++r) ws[t][r] = 0.f;

    for (int h = 0; h < HH; ++h) {
        const _Float16* qb = qd + ((size_t)(b*HH + h))*SS*DH;
        const _Float16* kb = kd + ((size_t)(b*HH + h))*SS*DH;
        f16x8 aq0 = *(const f16x8*)(qb + (size_t)qrow*DH +      g*8);
        f16x8 aq1 = *(const f16x8*)(qb + (size_t)qrow*DH + 32 + g*8);
        float2 st[4];
        #pragma unroll
        for (int r = 0; r < 4; ++r)
            st[r] = stats[((size_t)(b*HH + h))*SS + i0 + rh*16 + g*4 + r];

        #pragma unroll
        for (int t = 0; t < 3; ++t) {
            int lt = cg2 + t*2;
            int c = z*6 + lt;
            if (c < NC) {
                int jj = c*16 + l15;
                int j  = jlo + jj;
                f16x8 bk0 = *(const f16x8*)(kb + (size_t)j*DH +      g*8);
                f16x8 bk1 = *(const f16x8*)(kb + (size_t)j*DH + 32 + g*8);
                f32x4 s = {0.f, 0.f, 0.f, 0.f};
                s = __builtin_amdgcn_mfma_f32_16x16x32_f16(aq0, bk0, s, 0, 0, 0);
                s = __builtin_amdgcn_mfma_f32_16x16x32_f16(aq1, bk1, s, 0, 0, 0);
                #pragma unroll
                for (int r = 0; r < 4; ++r) {
                    int i = i0 + rh*16 + g*4 + r;
                    int dd = i - j; if (dd < 0) dd = -dd;
                    if (dd <= WW)
                        ws[t][r] += __expf(s[r]*0.125f - st[r].x) * st[r].y;
                }
            }
        }
    }

    #pragma unroll
    for (int t = 0; t < 3; ++t) {
        int lt = cg2 + t*2, c = z*6 + lt;
        if (c < NC) {
            #pragma unroll
            for (int r = 0; r < 4; ++r)
                wacc[(rh*16 + g*4 + r)*WST + lt*16 + l15] = ws[t][r];
        }
    }
    __syncthreads();

    int lo, hi;
    if (z == 0)      { lo = 0;        hi = jlo + 96; }
    else if (z == 1) { lo = jlo + 96; hi = (jlo + 192 < SS) ? jlo + 192 : SS; }
    else             { lo = (jlo + 192 < SS) ? jlo + 192 : SS; hi = SS; }

    const int row = tid >> 3;
    const int pt  = tid & 7;
    const int i = i0 + row;
    const int blo = (i - WW > 0) ? i - WW : 0;
    const int bhi = (i + WW < SS - 1) ? i + WW : SS - 1;
    const int cbase = jlo + z*96;
    float* wrow = wout + ((size_t)(b*SS + i))*SS;
    for (int j4 = lo + pt*4; j4 < hi; j4 += 32) {
        float4 o;
        float* oo = (float*)&o;
        #pragma unroll
        for (int e = 0; e < 4; ++e) {
            int j = j4 + e;
            oo[e] = (j >= blo && j <= bhi)
                  ? wacc[row*WST + (j - cbase)] * 0.125f : 0.f;
        }
        *(float4*)(wrow + j4) = o;
    }
}

__global__ void pool_final(const float* __restrict__ part, float* __restrict__ pooled)
{
    int e = blockIdx.x * 256 + threadIdx.x;   // grid.x = 2
    int b = blockIdx.y;
    float m = -1e30f;
    #pragma unroll
    for (int t = 0; t < 16; ++t)
        m = fmaxf(m, part[((size_t)(b*16 + t))*EE + e]);
    pooled[b*EE + e] = m;
}

// ---------------------------------------------------------------------------
extern "C" void kernel_launch(void* const* d_in, const int* in_sizes, int n_in,
                              void* d_out, int out_size, void* d_ws, size_t ws_size,
                              hipStream_t stream)
{
    const float* emb = (const float*)d_in[0];
    const float* ipw = (const float*)d_in[1];
    const float* ipb = (const float*)d_in[2];
    const float* ow  = (const float*)d_in[3];
    const float* ob  = (const float*)d_in[4];

    float* pooled = (float*)d_out;                       // [4,512]
    float* wout   = pooled + (size_t)BB*EE;              // [4,2048,2048]

    const size_t headsz = (size_t)BB*HH*SS*DH;
    _Float16* q    = (_Float16*)d_ws;
    _Float16* k    = q + headsz;
    _Float16* v    = k + headsz;
    _Float16* ctx  = v + headsz;                         // [8192,512] fp16
    _Float16* A16  = ctx + (size_t)MM*EE;                // emb fp16
    _Float16* W16  = A16 + (size_t)MM*EE;                // in_proj_w fp16
    _Float16* OW16 = W16 + (size_t)3*EE*EE;              // out_w fp16
    float* part    = (float*)(OW16 + (size_t)EE*EE);     // [64,512]
    float2* stats  = (float2*)(part + 64*EE);            // [4,8,2048]

    convert3<<<1280, 256, 0, stream>>>(emb, ipw, ow, A16, W16, OW16);
    qkv_mfma<<<dim3(64, 12), 256, 0, stream>>>(A16, W16, ipb, q, k, v);
    attn_mfma<<<dim3(NTILE, BB, HH), 512, 0, stream>>>(q, k, v, ctx, stats);
    weights_k<<<dim3(NTILE, BB, 3), 256, 0, stream>>>(q, k, stats, wout);
    out_mfma<<<dim3(64, 4), 256, 0, stream>>>(ctx, OW16, ob, part);
    pool_final<<<dim3(2, BB), 256, 0, stream>>>(part, pooled);
}